// Round 2
// baseline (523.972 us; speedup 1.0000x reference)
//
#include <hip/hip_runtime.h>
#include <math.h>

#define BATCH   4
#define N1      2048
#define N2      8192
#define F       256
#define NTOT1   (BATCH * N1)    // 8192
#define NTOT2   (BATCH * N2)    // 32768
#define BN_EPS  1e-5f

#define S_SLICES  8
#define SLICE_PTS (N1 / S_SLICES)   // 256
#define QPB       512               // queries per block in knn_partial

// ---------------- zero the stats accumulators (ws is poisoned 0xAA) ----------
__global__ void zero_stats_kernel(float* sums) {
    int t = threadIdx.x;
    #pragma unroll
    for (int i = 0; i < 4; ++i) sums[t + 256 * i] = 0.0f;
}

// ---------------- GEMM: H[M,256] = X[M,256] @ W[256,256] + bias --------------
__global__ __launch_bounds__(256) void gemm_kernel(const float* __restrict__ X,
                                                   const float* __restrict__ W,
                                                   const float* __restrict__ bias,
                                                   float* __restrict__ H) {
    __shared__ float xs[32][256];
    const int row0 = blockIdx.x * 32;
    const int t  = threadIdx.x;
    const int cg = t & 63;
    const int rg = t >> 6;

    #pragma unroll
    for (int s = 0; s < 32; ++s)
        xs[s][t] = X[(size_t)(row0 + s) * F + t];
    __syncthreads();

    float acc[4][8];
    #pragma unroll
    for (int j = 0; j < 4; ++j)
        #pragma unroll
        for (int rr = 0; rr < 8; ++rr) acc[j][rr] = 0.0f;

    for (int k = 0; k < 256; k += 4) {
        float wv[4][4];
        #pragma unroll
        for (int kk = 0; kk < 4; ++kk)
            #pragma unroll
            for (int j = 0; j < 4; ++j)
                wv[kk][j] = W[(size_t)(k + kk) * F + cg + 64 * j];
        #pragma unroll
        for (int rr = 0; rr < 8; ++rr) {
            const float4 x4 = *(const float4*)&xs[rg * 8 + rr][k];
            #pragma unroll
            for (int j = 0; j < 4; ++j) {
                acc[j][rr] = fmaf(x4.x, wv[0][j], acc[j][rr]);
                acc[j][rr] = fmaf(x4.y, wv[1][j], acc[j][rr]);
                acc[j][rr] = fmaf(x4.z, wv[2][j], acc[j][rr]);
                acc[j][rr] = fmaf(x4.w, wv[3][j], acc[j][rr]);
            }
        }
    }

    float bv[4];
    #pragma unroll
    for (int j = 0; j < 4; ++j) bv[j] = bias[cg + 64 * j];
    #pragma unroll
    for (int rr = 0; rr < 8; ++rr)
        #pragma unroll
        for (int j = 0; j < 4; ++j)
            H[(size_t)(row0 + rg * 8 + rr) * F + cg + 64 * j] = acc[j][rr] + bv[j];
}

// ---------------- per-feature sum & sumsq (for BN batch stats) ---------------
__global__ __launch_bounds__(256) void stats_kernel(const float* __restrict__ H,
                                                    int rows_per_block,
                                                    float* __restrict__ sum,
                                                    float* __restrict__ sumsq) {
    const int t = threadIdx.x;
    const size_t base = (size_t)blockIdx.x * rows_per_block * F;
    float s = 0.0f, q = 0.0f;
    for (int r = 0; r < rows_per_block; ++r) {
        const float v = H[base + (size_t)r * F + t];
        s += v;
        q = fmaf(v, v, q);
    }
    atomicAdd(&sum[t], s);
    atomicAdd(&sumsq[t], q);
}

// ---------------- fold BN into scale/shift: out = s*h + t --------------------
__global__ void finalize_kernel(const float* __restrict__ sums,
                                const float* __restrict__ g1, const float* __restrict__ be1,
                                const float* __restrict__ g2, const float* __restrict__ be2,
                                float* __restrict__ ss) {
    const int t = threadIdx.x;
    const float m1 = sums[t] * (1.0f / (float)NTOT1);
    const float v1 = sums[256 + t] * (1.0f / (float)NTOT1) - m1 * m1;
    const float s1 = g1[t] * rsqrtf(v1 + BN_EPS);
    ss[t]       = s1;
    ss[256 + t] = be1[t] - m1 * s1;
    const float m2 = sums[512 + t] * (1.0f / (float)NTOT2);
    const float v2 = sums[768 + t] * (1.0f / (float)NTOT2) - m2 * m2;
    const float s2 = g2[t] * rsqrtf(v2 + BN_EPS);
    ss[512 + t] = s2;
    ss[768 + t] = be2[t] - m2 * s2;
}

// ---------------- top-3 insert (strict < keeps first-occurrence ties) --------
__device__ __forceinline__ void ins3(float d, int j,
                                     float& d0, float& d1, float& d2,
                                     int& j0, int& j1, int& j2) {
    if (d < d2) {
        if (d < d1) {
            d2 = d1; j2 = j1;
            if (d < d0) { d1 = d0; j1 = j0; d0 = d; j0 = j; }
            else        { d1 = d;  j1 = j; }
        } else { d2 = d; j2 = j; }
    }
}

// ---------------- kNN stage 1: partial top-3 per (query, slice) --------------
// grid = (NTOT2/QPB, S_SLICES); block = 256; 2 queries per thread
__global__ __launch_bounds__(256) void knn_partial_kernel(const float* __restrict__ p1,
                                                          const float* __restrict__ p2,
                                                          float* __restrict__ pd,
                                                          int* __restrict__ pi) {
    __shared__ float4 ls[SLICE_PTS];
    const int qbase = blockIdx.x * QPB;
    const int slice = blockIdx.y;
    const int b = qbase >> 13;              // / N2
    const int t = threadIdx.x;

    {
        const int j = slice * SLICE_PTS + t;
        const size_t base = (size_t)(b * N1 + j) * 3;
        ls[t] = make_float4(p1[base + 0], p1[base + 1], p1[base + 2], 0.0f);
    }
    __syncthreads();

    const int iq0 = qbase + t;
    const int iq1 = qbase + 256 + t;
    const float qx0 = p2[(size_t)iq0 * 3 + 0];
    const float qy0 = p2[(size_t)iq0 * 3 + 1];
    const float qz0 = p2[(size_t)iq0 * 3 + 2];
    const float qx1 = p2[(size_t)iq1 * 3 + 0];
    const float qy1 = p2[(size_t)iq1 * 3 + 1];
    const float qz1 = p2[(size_t)iq1 * 3 + 2];

    float a0 = 1e30f, a1 = 1e30f, a2 = 1e30f; int ai0 = 0, ai1 = 0, ai2 = 0;
    float c0 = 1e30f, c1 = 1e30f, c2 = 1e30f; int ci0 = 0, ci1 = 0, ci2 = 0;

    #pragma unroll 4
    for (int jj = 0; jj < SLICE_PTS; ++jj) {
        const float4 p = ls[jj];        // wave-uniform address: broadcast, conflict-free
        {
            const float dx = p.x - qx0, dy = p.y - qy0, dz = p.z - qz0;
            float d = dx * dx; d = fmaf(dy, dy, d); d = fmaf(dz, dz, d);
            ins3(d, jj, a0, a1, a2, ai0, ai1, ai2);
        }
        {
            const float dx = p.x - qx1, dy = p.y - qy1, dz = p.z - qz1;
            float d = dx * dx; d = fmaf(dy, dy, d); d = fmaf(dz, dz, d);
            ins3(d, jj, c0, c1, c2, ci0, ci1, ci2);
        }
    }

    const int jb = slice * SLICE_PTS;   // batch-local base index of this slice
    {
        const size_t o = ((size_t)iq0 * S_SLICES + slice) * 3;
        pd[o + 0] = a0; pd[o + 1] = a1; pd[o + 2] = a2;
        pi[o + 0] = jb + ai0; pi[o + 1] = jb + ai1; pi[o + 2] = jb + ai2;
    }
    {
        const size_t o = ((size_t)iq1 * S_SLICES + slice) * 3;
        pd[o + 0] = c0; pd[o + 1] = c1; pd[o + 2] = c2;
        pi[o + 0] = jb + ci0; pi[o + 1] = jb + ci1; pi[o + 2] = jb + ci2;
    }
}

// ---------------- kNN stage 2: merge partials, compute weights ---------------
__global__ __launch_bounds__(256) void knn_merge_kernel(const float* __restrict__ pd,
                                                        const int* __restrict__ pi,
                                                        int* __restrict__ idx_out,
                                                        float* __restrict__ w_out) {
    const int i = blockIdx.x * 256 + threadIdx.x;   // query
    const int b = i >> 13;

    float d0 = 1e30f, d1 = 1e30f, d2 = 1e30f;
    int   j0 = 0,     j1 = 0,     j2 = 0;

    #pragma unroll
    for (int s = 0; s < S_SLICES; ++s) {
        const size_t o = ((size_t)i * S_SLICES + s) * 3;
        #pragma unroll
        for (int k = 0; k < 3; ++k)
            ins3(pd[o + k], pi[o + k], d0, d1, d2, j0, j1, j2);
    }

    const float w0 = 1.0f / fmaxf(d0, 1e-16f);
    const float w1 = 1.0f / fmaxf(d1, 1e-16f);
    const float w2 = 1.0f / fmaxf(d2, 1e-16f);
    const float inv = 1.0f / (w0 + w1 + w2);

    idx_out[(size_t)i * 3 + 0] = b * N1 + j0;
    idx_out[(size_t)i * 3 + 1] = b * N1 + j1;
    idx_out[(size_t)i * 3 + 2] = b * N1 + j2;
    w_out[(size_t)i * 3 + 0] = w0 * inv;
    w_out[(size_t)i * 3 + 1] = w1 * inv;
    w_out[(size_t)i * 3 + 2] = w2 * inv;
}

// ---------------- interpolate + BN-apply + add + write -----------------------
__global__ __launch_bounds__(256) void interp_kernel(const float* __restrict__ h1,
                                                     const float* __restrict__ h2,
                                                     const int* __restrict__ idx,
                                                     const float* __restrict__ w,
                                                     const float* __restrict__ ss,
                                                     float* __restrict__ out) {
    const int i = blockIdx.x;
    const int t = threadIdx.x;

    const int   j0 = idx[(size_t)i * 3 + 0];
    const int   j1 = idx[(size_t)i * 3 + 1];
    const int   j2 = idx[(size_t)i * 3 + 2];
    const float w0 = w[(size_t)i * 3 + 0];
    const float w1 = w[(size_t)i * 3 + 1];
    const float w2 = w[(size_t)i * 3 + 2];

    const float s1 = ss[t],       t1 = ss[256 + t];
    const float s2 = ss[512 + t], t2 = ss[768 + t];

    float a = w0 * h1[(size_t)j0 * F + t];
    a = fmaf(w1, h1[(size_t)j1 * F + t], a);
    a = fmaf(w2, h1[(size_t)j2 * F + t], a);

    const float o = fmaf(a, s1, t1) + fmaf(h2[(size_t)i * F + t], s2, t2);
    out[(size_t)i * F + t] = o;
}

// ---------------- passthrough tail: positions_2 + batch_2 --------------------
__global__ __launch_bounds__(256) void tail_kernel(const float* __restrict__ pos2,
                                                   float* __restrict__ out) {
    const int i = blockIdx.x * 256 + threadIdx.x;
    if (i < NTOT2 * 3) out[(size_t)NTOT2 * F + i] = pos2[i];
    if (i < NTOT2)     out[(size_t)NTOT2 * F + NTOT2 * 3 + i] = (float)(i >> 13);
}

// -----------------------------------------------------------------------------
extern "C" void kernel_launch(void* const* d_in, const int* in_sizes, int n_in,
                              void* d_out, int out_size, void* d_ws, size_t ws_size,
                              hipStream_t stream) {
    const float* f1  = (const float*)d_in[0];
    const float* p1  = (const float*)d_in[1];
    const float* f2  = (const float*)d_in[3];
    const float* p2  = (const float*)d_in[4];
    const float* W1  = (const float*)d_in[6];
    const float* b1  = (const float*)d_in[7];
    const float* g1  = (const float*)d_in[8];
    const float* be1 = (const float*)d_in[9];
    const float* W2  = (const float*)d_in[10];
    const float* b2  = (const float*)d_in[11];
    const float* g2  = (const float*)d_in[12];
    const float* be2 = (const float*)d_in[13];

    char* ws = (char*)d_ws;
    float* h1      = (float*)(ws);                    //  8,388,608 B
    float* h2      = (float*)(ws + 8388608);          // 33,554,432 B
    float* sums    = (float*)(ws + 41943040);         //      4,096 B
    float* ssbuf   = (float*)(ws + 41947136);         //      4,096 B
    int*   knn_idx = (int*)  (ws + 41951232);         //    393,216 B
    float* knn_w   = (float*)(ws + 42344448);         //    393,216 B
    float* pd      = (float*)(ws + 42737664);         //  3,145,728 B
    int*   pi      = (int*)  (ws + 45883392);         //  3,145,728 B
    float* out     = (float*)d_out;

    zero_stats_kernel<<<1, 256, 0, stream>>>(sums);

    gemm_kernel<<<NTOT1 / 32, 256, 0, stream>>>(f1, W1, b1, h1);
    gemm_kernel<<<NTOT2 / 32, 256, 0, stream>>>(f2, W2, b2, h2);

    stats_kernel<<<64,  256, 0, stream>>>(h1, NTOT1 / 64,  sums,       sums + 256);
    stats_kernel<<<256, 256, 0, stream>>>(h2, NTOT2 / 256, sums + 512, sums + 768);

    finalize_kernel<<<1, 256, 0, stream>>>(sums, g1, be1, g2, be2, ssbuf);

    dim3 kgrid(NTOT2 / QPB, S_SLICES);
    knn_partial_kernel<<<kgrid, 256, 0, stream>>>(p1, p2, pd, pi);
    knn_merge_kernel<<<NTOT2 / 256, 256, 0, stream>>>(pd, pi, knn_idx, knn_w);

    interp_kernel<<<NTOT2, 256, 0, stream>>>(h1, h2, knn_idx, knn_w, ssbuf, out);

    tail_kernel<<<(NTOT2 * 3 + 255) / 256, 256, 0, stream>>>(p2, out);
}

// Round 3
// 341.481 us; speedup vs baseline: 1.5344x; 1.5344x over previous
//
#include <hip/hip_runtime.h>
#include <math.h>

#define BATCH   4
#define N1      2048
#define N2      8192
#define F       256
#define NTOT1   (BATCH * N1)    // 8192
#define NTOT2   (BATCH * N2)    // 32768
#define BN_EPS  1e-5f

#define S_SLICES  8
#define SLICE_PTS (N1 / S_SLICES)   // 256
#define QPB       512               // queries per block in knn_partial

// ---------------- zero the stats accumulators (ws is poisoned 0xAA) ----------
__global__ void zero_stats_kernel(float* sums) {
    int t = threadIdx.x;
    #pragma unroll
    for (int i = 0; i < 4; ++i) sums[t + 256 * i] = 0.0f;
}

// ---------------- GEMM: H[M,256] = X[M,256] @ W[256,256] + bias --------------
__global__ __launch_bounds__(256) void gemm_kernel(const float* __restrict__ X,
                                                   const float* __restrict__ W,
                                                   const float* __restrict__ bias,
                                                   float* __restrict__ H) {
    __shared__ float xs[32][256];
    const int row0 = blockIdx.x * 32;
    const int t  = threadIdx.x;
    const int cg = t & 63;
    const int rg = t >> 6;

    #pragma unroll
    for (int s = 0; s < 32; ++s)
        xs[s][t] = X[(size_t)(row0 + s) * F + t];
    __syncthreads();

    float acc[4][8];
    #pragma unroll
    for (int j = 0; j < 4; ++j)
        #pragma unroll
        for (int rr = 0; rr < 8; ++rr) acc[j][rr] = 0.0f;

    for (int k = 0; k < 256; k += 4) {
        float wv[4][4];
        #pragma unroll
        for (int kk = 0; kk < 4; ++kk)
            #pragma unroll
            for (int j = 0; j < 4; ++j)
                wv[kk][j] = W[(size_t)(k + kk) * F + cg + 64 * j];
        #pragma unroll
        for (int rr = 0; rr < 8; ++rr) {
            const float4 x4 = *(const float4*)&xs[rg * 8 + rr][k];
            #pragma unroll
            for (int j = 0; j < 4; ++j) {
                acc[j][rr] = fmaf(x4.x, wv[0][j], acc[j][rr]);
                acc[j][rr] = fmaf(x4.y, wv[1][j], acc[j][rr]);
                acc[j][rr] = fmaf(x4.z, wv[2][j], acc[j][rr]);
                acc[j][rr] = fmaf(x4.w, wv[3][j], acc[j][rr]);
            }
        }
    }

    float bv[4];
    #pragma unroll
    for (int j = 0; j < 4; ++j) bv[j] = bias[cg + 64 * j];
    #pragma unroll
    for (int rr = 0; rr < 8; ++rr)
        #pragma unroll
        for (int j = 0; j < 4; ++j)
            H[(size_t)(row0 + rg * 8 + rr) * F + cg + 64 * j] = acc[j][rr] + bv[j];
}

// ---------------- per-feature sum & sumsq (for BN batch stats) ---------------
__global__ __launch_bounds__(256) void stats_kernel(const float* __restrict__ H,
                                                    int rows_per_block,
                                                    float* __restrict__ sum,
                                                    float* __restrict__ sumsq) {
    const int t = threadIdx.x;
    const size_t base = (size_t)blockIdx.x * rows_per_block * F;
    float s = 0.0f, q = 0.0f;
    for (int r = 0; r < rows_per_block; ++r) {
        const float v = H[base + (size_t)r * F + t];
        s += v;
        q = fmaf(v, v, q);
    }
    atomicAdd(&sum[t], s);
    atomicAdd(&sumsq[t], q);
}

// ---------------- fold BN into scale/shift: out = s*h + t --------------------
__global__ void finalize_kernel(const float* __restrict__ sums,
                                const float* __restrict__ g1, const float* __restrict__ be1,
                                const float* __restrict__ g2, const float* __restrict__ be2,
                                float* __restrict__ ss) {
    const int t = threadIdx.x;
    const float m1 = sums[t] * (1.0f / (float)NTOT1);
    const float v1 = sums[256 + t] * (1.0f / (float)NTOT1) - m1 * m1;
    const float s1 = g1[t] * rsqrtf(v1 + BN_EPS);
    ss[t]       = s1;
    ss[256 + t] = be1[t] - m1 * s1;
    const float m2 = sums[512 + t] * (1.0f / (float)NTOT2);
    const float v2 = sums[768 + t] * (1.0f / (float)NTOT2) - m2 * m2;
    const float s2 = g2[t] * rsqrtf(v2 + BN_EPS);
    ss[512 + t] = s2;
    ss[768 + t] = be2[t] - m2 * s2;
}

// ---------------- branchless top-3 insert (strict < keeps first ties) --------
// 3 v_cmp + 10 v_cndmask, no exec-mask divergence, fully pipelineable.
__device__ __forceinline__ void ins3b(float d, int j,
                                      float& d0, float& d1, float& d2,
                                      int& j0, int& j1, int& j2) {
    const bool c0 = d < d0;
    const bool c1 = d < d1;
    const bool c2 = d < d2;
    d2 = c1 ? d1 : (c2 ? d : d2);
    j2 = c1 ? j1 : (c2 ? j : j2);
    d1 = c0 ? d0 : (c1 ? d : d1);
    j1 = c0 ? j0 : (c1 ? j : j1);
    d0 = c0 ? d  : d0;
    j0 = c0 ? j  : j0;
}

// ---------------- kNN stage 1: partial top-3 per (query, slice) --------------
// grid = (NTOT2/QPB, S_SLICES); block = 256; 2 queries per thread.
// Partial layout is [slice][query] so wave stores are contiguous.
__global__ __launch_bounds__(256) void knn_partial_kernel(const float* __restrict__ p1,
                                                          const float* __restrict__ p2,
                                                          float* __restrict__ pd,
                                                          int* __restrict__ pi) {
    __shared__ float4 ls[SLICE_PTS];
    const int qbase = blockIdx.x * QPB;
    const int slice = blockIdx.y;
    const int b = qbase >> 13;              // / N2
    const int t = threadIdx.x;

    {
        const int j = slice * SLICE_PTS + t;
        const size_t base = (size_t)(b * N1 + j) * 3;
        ls[t] = make_float4(p1[base + 0], p1[base + 1], p1[base + 2], 0.0f);
    }
    __syncthreads();

    const int iq0 = qbase + t;
    const int iq1 = qbase + 256 + t;
    const float qx0 = p2[(size_t)iq0 * 3 + 0];
    const float qy0 = p2[(size_t)iq0 * 3 + 1];
    const float qz0 = p2[(size_t)iq0 * 3 + 2];
    const float qx1 = p2[(size_t)iq1 * 3 + 0];
    const float qy1 = p2[(size_t)iq1 * 3 + 1];
    const float qz1 = p2[(size_t)iq1 * 3 + 2];

    float a0 = 1e30f, a1 = 1e30f, a2 = 1e30f; int ai0 = 0, ai1 = 0, ai2 = 0;
    float c0 = 1e30f, c1 = 1e30f, c2 = 1e30f; int ci0 = 0, ci1 = 0, ci2 = 0;

    #pragma unroll 8
    for (int jj = 0; jj < SLICE_PTS; ++jj) {
        const float4 p = ls[jj];        // wave-uniform broadcast, conflict-free
        {
            const float dx = p.x - qx0, dy = p.y - qy0, dz = p.z - qz0;
            float d = dx * dx; d = fmaf(dy, dy, d); d = fmaf(dz, dz, d);
            ins3b(d, jj, a0, a1, a2, ai0, ai1, ai2);
        }
        {
            const float dx = p.x - qx1, dy = p.y - qy1, dz = p.z - qz1;
            float d = dx * dx; d = fmaf(dy, dy, d); d = fmaf(dz, dz, d);
            ins3b(d, jj, c0, c1, c2, ci0, ci1, ci2);
        }
    }

    const int jb = slice * SLICE_PTS;   // batch-local base index of this slice
    {
        const size_t o = ((size_t)slice * NTOT2 + iq0) * 3;
        pd[o + 0] = a0; pd[o + 1] = a1; pd[o + 2] = a2;
        pi[o + 0] = jb + ai0; pi[o + 1] = jb + ai1; pi[o + 2] = jb + ai2;
    }
    {
        const size_t o = ((size_t)slice * NTOT2 + iq1) * 3;
        pd[o + 0] = c0; pd[o + 1] = c1; pd[o + 2] = c2;
        pi[o + 0] = jb + ci0; pi[o + 1] = jb + ci1; pi[o + 2] = jb + ci2;
    }
}

// ---------------- kNN stage 2: merge partials, compute weights ---------------
__global__ __launch_bounds__(256) void knn_merge_kernel(const float* __restrict__ pd,
                                                        const int* __restrict__ pi,
                                                        int* __restrict__ idx_out,
                                                        float* __restrict__ w_out) {
    const int i = blockIdx.x * 256 + threadIdx.x;   // query
    const int b = i >> 13;

    float d0 = 1e30f, d1 = 1e30f, d2 = 1e30f;
    int   j0 = 0,     j1 = 0,     j2 = 0;

    #pragma unroll
    for (int s = 0; s < S_SLICES; ++s) {
        const size_t o = ((size_t)s * NTOT2 + i) * 3;
        #pragma unroll
        for (int k = 0; k < 3; ++k)
            ins3b(pd[o + k], pi[o + k], d0, d1, d2, j0, j1, j2);
    }

    const float w0 = 1.0f / fmaxf(d0, 1e-16f);
    const float w1 = 1.0f / fmaxf(d1, 1e-16f);
    const float w2 = 1.0f / fmaxf(d2, 1e-16f);
    const float inv = 1.0f / (w0 + w1 + w2);

    idx_out[(size_t)i * 3 + 0] = b * N1 + j0;
    idx_out[(size_t)i * 3 + 1] = b * N1 + j1;
    idx_out[(size_t)i * 3 + 2] = b * N1 + j2;
    w_out[(size_t)i * 3 + 0] = w0 * inv;
    w_out[(size_t)i * 3 + 1] = w1 * inv;
    w_out[(size_t)i * 3 + 2] = w2 * inv;
}

// ---------------- interpolate + BN-apply + add + write -----------------------
__global__ __launch_bounds__(256) void interp_kernel(const float* __restrict__ h1,
                                                     const float* __restrict__ h2,
                                                     const int* __restrict__ idx,
                                                     const float* __restrict__ w,
                                                     const float* __restrict__ ss,
                                                     float* __restrict__ out) {
    const int i = blockIdx.x;
    const int t = threadIdx.x;

    const int   j0 = idx[(size_t)i * 3 + 0];
    const int   j1 = idx[(size_t)i * 3 + 1];
    const int   j2 = idx[(size_t)i * 3 + 2];
    const float w0 = w[(size_t)i * 3 + 0];
    const float w1 = w[(size_t)i * 3 + 1];
    const float w2 = w[(size_t)i * 3 + 2];

    const float s1 = ss[t],       t1 = ss[256 + t];
    const float s2 = ss[512 + t], t2 = ss[768 + t];

    float a = w0 * h1[(size_t)j0 * F + t];
    a = fmaf(w1, h1[(size_t)j1 * F + t], a);
    a = fmaf(w2, h1[(size_t)j2 * F + t], a);

    const float o = fmaf(a, s1, t1) + fmaf(h2[(size_t)i * F + t], s2, t2);
    out[(size_t)i * F + t] = o;
}

// ---------------- passthrough tail: positions_2 + batch_2 --------------------
__global__ __launch_bounds__(256) void tail_kernel(const float* __restrict__ pos2,
                                                   float* __restrict__ out) {
    const int i = blockIdx.x * 256 + threadIdx.x;
    if (i < NTOT2 * 3) out[(size_t)NTOT2 * F + i] = pos2[i];
    if (i < NTOT2)     out[(size_t)NTOT2 * F + NTOT2 * 3 + i] = (float)(i >> 13);
}

// -----------------------------------------------------------------------------
extern "C" void kernel_launch(void* const* d_in, const int* in_sizes, int n_in,
                              void* d_out, int out_size, void* d_ws, size_t ws_size,
                              hipStream_t stream) {
    const float* f1  = (const float*)d_in[0];
    const float* p1  = (const float*)d_in[1];
    const float* f2  = (const float*)d_in[3];
    const float* p2  = (const float*)d_in[4];
    const float* W1  = (const float*)d_in[6];
    const float* b1  = (const float*)d_in[7];
    const float* g1  = (const float*)d_in[8];
    const float* be1 = (const float*)d_in[9];
    const float* W2  = (const float*)d_in[10];
    const float* b2  = (const float*)d_in[11];
    const float* g2  = (const float*)d_in[12];
    const float* be2 = (const float*)d_in[13];

    char* ws = (char*)d_ws;
    float* h1      = (float*)(ws);                    //  8,388,608 B
    float* h2      = (float*)(ws + 8388608);          // 33,554,432 B
    float* sums    = (float*)(ws + 41943040);         //      4,096 B
    float* ssbuf   = (float*)(ws + 41947136);         //      4,096 B
    int*   knn_idx = (int*)  (ws + 41951232);         //    393,216 B
    float* knn_w   = (float*)(ws + 42344448);         //    393,216 B
    float* pd      = (float*)(ws + 42737664);         //  3,145,728 B
    int*   pi      = (int*)  (ws + 45883392);         //  3,145,728 B
    float* out     = (float*)d_out;

    zero_stats_kernel<<<1, 256, 0, stream>>>(sums);

    gemm_kernel<<<NTOT1 / 32, 256, 0, stream>>>(f1, W1, b1, h1);
    gemm_kernel<<<NTOT2 / 32, 256, 0, stream>>>(f2, W2, b2, h2);

    stats_kernel<<<64,  256, 0, stream>>>(h1, NTOT1 / 64,  sums,       sums + 256);
    stats_kernel<<<256, 256, 0, stream>>>(h2, NTOT2 / 256, sums + 512, sums + 768);

    finalize_kernel<<<1, 256, 0, stream>>>(sums, g1, be1, g2, be2, ssbuf);

    dim3 kgrid(NTOT2 / QPB, S_SLICES);
    knn_partial_kernel<<<kgrid, 256, 0, stream>>>(p1, p2, pd, pi);
    knn_merge_kernel<<<NTOT2 / 256, 256, 0, stream>>>(pd, pi, knn_idx, knn_w);

    interp_kernel<<<NTOT2, 256, 0, stream>>>(h1, h2, knn_idx, knn_w, ssbuf, out);

    tail_kernel<<<(NTOT2 * 3 + 255) / 256, 256, 0, stream>>>(p2, out);
}

// Round 4
// 222.368 us; speedup vs baseline: 2.3563x; 1.5357x over previous
//
#include <hip/hip_runtime.h>
#include <math.h>

#define BATCH   4
#define N1      2048
#define N2      8192
#define F       256
#define NTOT1   (BATCH * N1)    // 8192
#define NTOT2   (BATCH * N2)    // 32768
#define BN_EPS  1e-5f

#define S_SLICES  8
#define SLICE_PTS (N1 / S_SLICES)   // 256
#define QPB       512

typedef __attribute__((ext_vector_type(8))) short bf16x8;
typedef __attribute__((ext_vector_type(4))) float f32x4;

// ---------------- helpers ----------------------------------------------------
__device__ __forceinline__ unsigned short f2bf(float f) {   // RNE f32->bf16
    unsigned u = __float_as_uint(f);
    unsigned r = (u + 0x7fffu + ((u >> 16) & 1u)) >> 16;
    return (unsigned short)r;
}

__device__ __forceinline__ void async16(const void* g, void* l) {
    __builtin_amdgcn_global_load_lds(
        (const __attribute__((address_space(1))) unsigned int*)g,
        (__attribute__((address_space(3))) unsigned int*)l, 16, 0, 0);
}

// ---------------- zero the stats accumulators --------------------------------
__global__ void zero_stats_kernel(float* sums) {
    int t = threadIdx.x;
    #pragma unroll
    for (int i = 0; i < 4; ++i) sums[t + 256 * i] = 0.0f;
}

// ---------------- W[256,256] f32 -> Wt[256,256] bf16, transposed [n][k] ------
__global__ __launch_bounds__(256) void convert_wt_kernel(const float* __restrict__ W,
                                                         unsigned short* __restrict__ Wt) {
    __shared__ float tile[64][65];
    const int tx = threadIdx.x & 63;
    const int ty = threadIdx.x >> 6;
    const int gx0 = blockIdx.x * 64;    // n block
    const int gy0 = blockIdx.y * 64;    // k block
    #pragma unroll
    for (int j = 0; j < 16; ++j) {
        const int row = ty * 16 + j;
        tile[row][tx] = W[(size_t)(gy0 + row) * 256 + gx0 + tx];
    }
    __syncthreads();
    #pragma unroll
    for (int j = 0; j < 16; ++j) {
        const int row = ty * 16 + j;    // output n within block
        Wt[(size_t)(gx0 + row) * 256 + gy0 + tx] = f2bf(tile[tx][row]);
    }
}

// ---------------- X f32 -> bf16 (RNE), vectorized ----------------------------
__global__ __launch_bounds__(256) void convert_x_kernel(const float4* __restrict__ X,
                                                        ushort4* __restrict__ Xb, int n4) {
    const int i = blockIdx.x * 256 + threadIdx.x;
    if (i < n4) {
        const float4 v = X[i];
        ushort4 o;
        o.x = f2bf(v.x); o.y = f2bf(v.y); o.z = f2bf(v.z); o.w = f2bf(v.w);
        Xb[i] = o;
    }
}

// ---------------- MFMA GEMM: H[M,256] = Xb @ Wt^T + bias; fused BN stats -----
// Xb bf16 [M][256] row-major; Wt bf16 [256 n][256 k]; H f32 [M][256].
// tile 128x128, 4 waves, each wave 64x64 = 4x4 MFMA 16x16x32, BK=32.
__global__ __launch_bounds__(256) void gemm_mfma_kernel(const unsigned short* __restrict__ Xb,
                                                        const unsigned short* __restrict__ Wt,
                                                        const float* __restrict__ bias,
                                                        float* __restrict__ H,
                                                        float* __restrict__ sum,
                                                        float* __restrict__ sumsq) {
    __shared__ unsigned short As[128 * 32];   // 8 KB, [row][k] k-contiguous
    __shared__ unsigned short Bs[128 * 32];   // 8 KB, [n][k]

    const int t    = threadIdx.x;
    const int wave = t >> 6;
    const int lane = t & 63;
    const int row0 = blockIdx.x * 128;
    const int n0   = blockIdx.y * 128;
    const int wm   = (wave & 1) * 64;
    const int wn   = (wave >> 1) * 64;
    const int ml   = lane & 15;
    const int q    = lane >> 4;

    f32x4 acc[4][4] = {};

    for (int kt = 0; kt < 256; kt += 32) {
        #pragma unroll
        for (int r = 0; r < 2; ++r) {
            const int e   = r * 2048 + t * 8;   // bf16 element index in 128x32 tile
            const int row = e >> 5;
            const int kk  = e & 31;
            async16(Xb + (size_t)(row0 + row) * 256 + kt + kk, (unsigned short*)As + e);
            async16(Wt + (size_t)(n0 + row) * 256 + kt + kk, (unsigned short*)Bs + e);
        }
        __syncthreads();   // drains vmcnt -> tiles resident

        bf16x8 af[4], bf[4];
        #pragma unroll
        for (int mt = 0; mt < 4; ++mt)
            af[mt] = *(const bf16x8*)&As[(wm + mt * 16 + ml) * 32 + q * 8];
        #pragma unroll
        for (int nt = 0; nt < 4; ++nt)
            bf[nt] = *(const bf16x8*)&Bs[(wn + nt * 16 + ml) * 32 + q * 8];
        #pragma unroll
        for (int mt = 0; mt < 4; ++mt)
            #pragma unroll
            for (int nt = 0; nt < 4; ++nt)
                acc[mt][nt] = __builtin_amdgcn_mfma_f32_16x16x32_bf16(af[mt], bf[nt],
                                                                      acc[mt][nt], 0, 0, 0);
        __syncthreads();
    }

    // epilogue: bias add, store, per-feature partial sums
    float bv[4], psum[4], psq[4];
    #pragma unroll
    for (int nt = 0; nt < 4; ++nt) {
        bv[nt] = bias[n0 + wn + nt * 16 + ml];
        psum[nt] = 0.0f; psq[nt] = 0.0f;
    }
    #pragma unroll
    for (int mt = 0; mt < 4; ++mt)
        #pragma unroll
        for (int nt = 0; nt < 4; ++nt)
            #pragma unroll
            for (int r = 0; r < 4; ++r) {
                const float v = acc[mt][nt][r] + bv[nt];
                const int grow = row0 + wm + mt * 16 + q * 4 + r;
                H[(size_t)grow * 256 + n0 + wn + nt * 16 + ml] = v;
                psum[nt] += v;
                psq[nt]  = fmaf(v, v, psq[nt]);
            }
    // reduce across the 4 quads (lanes ml, ml+16, ml+32, ml+48 share a column)
    #pragma unroll
    for (int nt = 0; nt < 4; ++nt) {
        psum[nt] += __shfl_xor(psum[nt], 16, 64);
        psum[nt] += __shfl_xor(psum[nt], 32, 64);
        psq[nt]  += __shfl_xor(psq[nt], 16, 64);
        psq[nt]  += __shfl_xor(psq[nt], 32, 64);
    }
    if (q == 0) {
        #pragma unroll
        for (int nt = 0; nt < 4; ++nt) {
            const int col = n0 + wn + nt * 16 + ml;
            atomicAdd(&sum[col],   psum[nt]);
            atomicAdd(&sumsq[col], psq[nt]);
        }
    }
}

// ---------------- fold BN into scale/shift: out = s*h + t --------------------
__global__ void finalize_kernel(const float* __restrict__ sums,
                                const float* __restrict__ g1, const float* __restrict__ be1,
                                const float* __restrict__ g2, const float* __restrict__ be2,
                                float* __restrict__ ss) {
    const int t = threadIdx.x;
    const float m1 = sums[t] * (1.0f / (float)NTOT1);
    const float v1 = sums[256 + t] * (1.0f / (float)NTOT1) - m1 * m1;
    const float s1 = g1[t] * rsqrtf(v1 + BN_EPS);
    ss[t]       = s1;
    ss[256 + t] = be1[t] - m1 * s1;
    const float m2 = sums[512 + t] * (1.0f / (float)NTOT2);
    const float v2 = sums[768 + t] * (1.0f / (float)NTOT2) - m2 * m2;
    const float s2 = g2[t] * rsqrtf(v2 + BN_EPS);
    ss[512 + t] = s2;
    ss[768 + t] = be2[t] - m2 * s2;
}

// ---------------- branchless top-3 insert ------------------------------------
__device__ __forceinline__ void ins3b(float d, int j,
                                      float& d0, float& d1, float& d2,
                                      int& j0, int& j1, int& j2) {
    const bool c0 = d < d0;
    const bool c1 = d < d1;
    const bool c2 = d < d2;
    d2 = c1 ? d1 : (c2 ? d : d2);
    j2 = c1 ? j1 : (c2 ? j : j2);
    d1 = c0 ? d0 : (c1 ? d : d1);
    j1 = c0 ? j0 : (c1 ? j : j1);
    d0 = c0 ? d  : d0;
    j0 = c0 ? j  : j0;
}

// ---------------- kNN stage 1: partial top-3 per (query, slice) --------------
__global__ __launch_bounds__(256) void knn_partial_kernel(const float* __restrict__ p1,
                                                          const float* __restrict__ p2,
                                                          float* __restrict__ pd,
                                                          int* __restrict__ pi) {
    __shared__ float4 ls[SLICE_PTS];
    const int qbase = blockIdx.x * QPB;
    const int slice = blockIdx.y;
    const int b = qbase >> 13;
    const int t = threadIdx.x;

    {
        const int j = slice * SLICE_PTS + t;
        const size_t base = (size_t)(b * N1 + j) * 3;
        ls[t] = make_float4(p1[base + 0], p1[base + 1], p1[base + 2], 0.0f);
    }
    __syncthreads();

    const int iq0 = qbase + t;
    const int iq1 = qbase + 256 + t;
    const float qx0 = p2[(size_t)iq0 * 3 + 0];
    const float qy0 = p2[(size_t)iq0 * 3 + 1];
    const float qz0 = p2[(size_t)iq0 * 3 + 2];
    const float qx1 = p2[(size_t)iq1 * 3 + 0];
    const float qy1 = p2[(size_t)iq1 * 3 + 1];
    const float qz1 = p2[(size_t)iq1 * 3 + 2];

    float a0 = 1e30f, a1 = 1e30f, a2 = 1e30f; int ai0 = 0, ai1 = 0, ai2 = 0;
    float c0 = 1e30f, c1 = 1e30f, c2 = 1e30f; int ci0 = 0, ci1 = 0, ci2 = 0;

    #pragma unroll 8
    for (int jj = 0; jj < SLICE_PTS; ++jj) {
        const float4 p = ls[jj];
        {
            const float dx = p.x - qx0, dy = p.y - qy0, dz = p.z - qz0;
            float d = dx * dx; d = fmaf(dy, dy, d); d = fmaf(dz, dz, d);
            ins3b(d, jj, a0, a1, a2, ai0, ai1, ai2);
        }
        {
            const float dx = p.x - qx1, dy = p.y - qy1, dz = p.z - qz1;
            float d = dx * dx; d = fmaf(dy, dy, d); d = fmaf(dz, dz, d);
            ins3b(d, jj, c0, c1, c2, ci0, ci1, ci2);
        }
    }

    const int jb = slice * SLICE_PTS;
    {
        const size_t o = ((size_t)slice * NTOT2 + iq0) * 3;
        pd[o + 0] = a0; pd[o + 1] = a1; pd[o + 2] = a2;
        pi[o + 0] = jb + ai0; pi[o + 1] = jb + ai1; pi[o + 2] = jb + ai2;
    }
    {
        const size_t o = ((size_t)slice * NTOT2 + iq1) * 3;
        pd[o + 0] = c0; pd[o + 1] = c1; pd[o + 2] = c2;
        pi[o + 0] = jb + ci0; pi[o + 1] = jb + ci1; pi[o + 2] = jb + ci2;
    }
}

// ---------------- kNN stage 2: merge, weights --------------------------------
__global__ __launch_bounds__(256) void knn_merge_kernel(const float* __restrict__ pd,
                                                        const int* __restrict__ pi,
                                                        int* __restrict__ idx_out,
                                                        float* __restrict__ w_out) {
    const int i = blockIdx.x * 256 + threadIdx.x;
    const int b = i >> 13;

    float d0 = 1e30f, d1 = 1e30f, d2 = 1e30f;
    int   j0 = 0,     j1 = 0,     j2 = 0;

    #pragma unroll
    for (int s = 0; s < S_SLICES; ++s) {
        const size_t o = ((size_t)s * NTOT2 + i) * 3;
        #pragma unroll
        for (int k = 0; k < 3; ++k)
            ins3b(pd[o + k], pi[o + k], d0, d1, d2, j0, j1, j2);
    }

    const float w0 = 1.0f / fmaxf(d0, 1e-16f);
    const float w1 = 1.0f / fmaxf(d1, 1e-16f);
    const float w2 = 1.0f / fmaxf(d2, 1e-16f);
    const float inv = 1.0f / (w0 + w1 + w2);

    idx_out[(size_t)i * 3 + 0] = b * N1 + j0;
    idx_out[(size_t)i * 3 + 1] = b * N1 + j1;
    idx_out[(size_t)i * 3 + 2] = b * N1 + j2;
    w_out[(size_t)i * 3 + 0] = w0 * inv;
    w_out[(size_t)i * 3 + 1] = w1 * inv;
    w_out[(size_t)i * 3 + 2] = w2 * inv;
}

// ---------------- interpolate + BN-apply + add + write -----------------------
__global__ __launch_bounds__(256) void interp_kernel(const float* __restrict__ h1,
                                                     const float* __restrict__ h2,
                                                     const int* __restrict__ idx,
                                                     const float* __restrict__ w,
                                                     const float* __restrict__ ss,
                                                     float* __restrict__ out) {
    const int i = blockIdx.x;
    const int t = threadIdx.x;

    const int   j0 = idx[(size_t)i * 3 + 0];
    const int   j1 = idx[(size_t)i * 3 + 1];
    const int   j2 = idx[(size_t)i * 3 + 2];
    const float w0 = w[(size_t)i * 3 + 0];
    const float w1 = w[(size_t)i * 3 + 1];
    const float w2 = w[(size_t)i * 3 + 2];

    const float s1 = ss[t],       t1 = ss[256 + t];
    const float s2 = ss[512 + t], t2 = ss[768 + t];

    float a = w0 * h1[(size_t)j0 * F + t];
    a = fmaf(w1, h1[(size_t)j1 * F + t], a);
    a = fmaf(w2, h1[(size_t)j2 * F + t], a);

    const float o = fmaf(a, s1, t1) + fmaf(h2[(size_t)i * F + t], s2, t2);
    out[(size_t)i * F + t] = o;
}

// ---------------- passthrough tail -------------------------------------------
__global__ __launch_bounds__(256) void tail_kernel(const float* __restrict__ pos2,
                                                   float* __restrict__ out) {
    const int i = blockIdx.x * 256 + threadIdx.x;
    if (i < NTOT2 * 3) out[(size_t)NTOT2 * F + i] = pos2[i];
    if (i < NTOT2)     out[(size_t)NTOT2 * F + NTOT2 * 3 + i] = (float)(i >> 13);
}

// -----------------------------------------------------------------------------
extern "C" void kernel_launch(void* const* d_in, const int* in_sizes, int n_in,
                              void* d_out, int out_size, void* d_ws, size_t ws_size,
                              hipStream_t stream) {
    const float* f1  = (const float*)d_in[0];
    const float* p1  = (const float*)d_in[1];
    const float* f2  = (const float*)d_in[3];
    const float* p2  = (const float*)d_in[4];
    const float* W1  = (const float*)d_in[6];
    const float* b1  = (const float*)d_in[7];
    const float* g1  = (const float*)d_in[8];
    const float* be1 = (const float*)d_in[9];
    const float* W2  = (const float*)d_in[10];
    const float* b2  = (const float*)d_in[11];
    const float* g2  = (const float*)d_in[12];
    const float* be2 = (const float*)d_in[13];

    char* ws = (char*)d_ws;
    float*          h1      = (float*)(ws);                     //  8,388,608
    float*          h2      = (float*)(ws + 8388608);           // 33,554,432
    float*          sums    = (float*)(ws + 41943040);          //      4,096
    float*          ssbuf   = (float*)(ws + 41947136);          //      4,096
    int*            knn_idx = (int*)  (ws + 41951232);          //    393,216
    float*          knn_w   = (float*)(ws + 42344448);          //    393,216
    unsigned short* Xb1     = (unsigned short*)(ws + 42737664); //  4,194,304
    unsigned short* Xb2     = (unsigned short*)(ws + 46931968); // 16,777,216
    unsigned short* Wt1     = (unsigned short*)(ws + 63709184); //    131,072
    unsigned short* Wt2     = (unsigned short*)(ws + 63840256); //    131,072
    // pd/pi alias the (dead-after-gemm) Xb region:
    float*          pd      = (float*)(ws + 42737664);          //  3,145,728
    int*            pi      = (int*)  (ws + 45883392);          //  3,145,728
    float*          out     = (float*)d_out;

    zero_stats_kernel<<<1, 256, 0, stream>>>(sums);

    dim3 tg(4, 4);
    convert_wt_kernel<<<tg, 256, 0, stream>>>(W1, Wt1);
    convert_wt_kernel<<<tg, 256, 0, stream>>>(W2, Wt2);
    convert_x_kernel<<<NTOT1 * F / 4 / 256, 256, 0, stream>>>((const float4*)f1, (ushort4*)Xb1, NTOT1 * F / 4);
    convert_x_kernel<<<NTOT2 * F / 4 / 256, 256, 0, stream>>>((const float4*)f2, (ushort4*)Xb2, NTOT2 * F / 4);

    dim3 g1d(NTOT1 / 128, 2), g2d(NTOT2 / 128, 2);
    gemm_mfma_kernel<<<g1d, 256, 0, stream>>>(Xb1, Wt1, b1, h1, sums,       sums + 256);
    gemm_mfma_kernel<<<g2d, 256, 0, stream>>>(Xb2, Wt2, b2, h2, sums + 512, sums + 768);

    finalize_kernel<<<1, 256, 0, stream>>>(sums, g1, be1, g2, be2, ssbuf);

    dim3 kgrid(NTOT2 / QPB, S_SLICES);
    knn_partial_kernel<<<kgrid, 256, 0, stream>>>(p1, p2, pd, pi);
    knn_merge_kernel<<<NTOT2 / 256, 256, 0, stream>>>(pd, pi, knn_idx, knn_w);

    interp_kernel<<<NTOT2, 256, 0, stream>>>(h1, h2, knn_idx, knn_w, ssbuf, out);

    tail_kernel<<<(NTOT2 * 3 + 255) / 256, 256, 0, stream>>>(p2, out);
}

// Round 5
// 196.087 us; speedup vs baseline: 2.6721x; 1.1340x over previous
//
#include <hip/hip_runtime.h>
#include <math.h>

#define BATCH   4
#define N1      2048
#define N2      8192
#define F       256
#define NTOT1   (BATCH * N1)    // 8192
#define NTOT2   (BATCH * N2)    // 32768
#define BN_EPS  1e-5f

typedef __attribute__((ext_vector_type(8))) short bf16x8;
typedef __attribute__((ext_vector_type(4))) float f32x4;

// ---------------- helpers ----------------------------------------------------
__device__ __forceinline__ unsigned short f2bf(float f) {   // RNE f32->bf16
    unsigned u = __float_as_uint(f);
    unsigned r = (u + 0x7fffu + ((u >> 16) & 1u)) >> 16;
    return (unsigned short)r;
}
__device__ __forceinline__ float bf2f(unsigned short u) {
    return __uint_as_float((unsigned)u << 16);
}
__device__ __forceinline__ void async16(const void* g, void* l) {
    __builtin_amdgcn_global_load_lds(
        (const __attribute__((address_space(1))) unsigned int*)g,
        (__attribute__((address_space(3))) unsigned int*)l, 16, 0, 0);
}
__device__ __forceinline__ void ins3b(float d, int j,
                                      float& d0, float& d1, float& d2,
                                      int& j0, int& j1, int& j2) {
    const bool c0 = d < d0;
    const bool c1 = d < d1;
    const bool c2 = d < d2;
    d2 = c1 ? d1 : (c2 ? d : d2);
    j2 = c1 ? j1 : (c2 ? j : j2);
    d1 = c0 ? d0 : (c1 ? d : d1);
    j1 = c0 ? j0 : (c1 ? j : j1);
    d0 = c0 ? d  : d0;
    j0 = c0 ? j  : j0;
}

// =============================================================================
// Dispatch 1: prep — X->bf16, W->bf16 transposed, zero stats. Flattened grid.
//   blocks [0,8192)        : convert f2 -> Xb2        (2,097,152 float4s)
//   blocks [8192,10240)    : convert f1 -> Xb1        (  524,288 float4s)
//   blocks [10240,10256)   : W1 -> Wt1 (16 blocks of 64x64)
//   blocks [10256,10272)   : W2 -> Wt2
//   block  10272           : zero sums[1024]
// =============================================================================
__global__ __launch_bounds__(256) void prep_kernel(const float4* __restrict__ f1,
                                                   const float4* __restrict__ f2,
                                                   const float* __restrict__ W1,
                                                   const float* __restrict__ W2,
                                                   ushort4* __restrict__ Xb1,
                                                   ushort4* __restrict__ Xb2,
                                                   unsigned short* __restrict__ Wt1,
                                                   unsigned short* __restrict__ Wt2,
                                                   float* __restrict__ sums) {
    const int bx = blockIdx.x;
    const int t  = threadIdx.x;

    if (bx < 8192) {                      // f2 -> Xb2
        const int i = bx * 256 + t;
        const float4 v = f2[i];
        ushort4 o;
        o.x = f2bf(v.x); o.y = f2bf(v.y); o.z = f2bf(v.z); o.w = f2bf(v.w);
        Xb2[i] = o;
    } else if (bx < 10240) {              // f1 -> Xb1
        const int i = (bx - 8192) * 256 + t;
        const float4 v = f1[i];
        ushort4 o;
        o.x = f2bf(v.x); o.y = f2bf(v.y); o.z = f2bf(v.z); o.w = f2bf(v.w);
        Xb1[i] = o;
    } else if (bx < 10272) {              // W transpose+convert
        __shared__ float tile[64][65];
        const int bb = bx - 10240;
        const bool second = bb >= 16;
        const int bl = second ? bb - 16 : bb;
        const float* W = second ? W2 : W1;
        unsigned short* Wt = second ? Wt2 : Wt1;
        const int gx0 = (bl & 3) * 64;    // n block
        const int gy0 = (bl >> 2) * 64;   // k block
        const int tx = t & 63;
        const int ty = t >> 6;
        #pragma unroll
        for (int j = 0; j < 16; ++j) {
            const int row = ty * 16 + j;
            tile[row][tx] = W[(size_t)(gy0 + row) * 256 + gx0 + tx];
        }
        __syncthreads();
        #pragma unroll
        for (int j = 0; j < 16; ++j) {
            const int row = ty * 16 + j;
            Wt[(size_t)(gx0 + row) * 256 + gy0 + tx] = f2bf(tile[tx][row]);
        }
    } else {                              // zero sums
        #pragma unroll
        for (int i = 0; i < 4; ++i) sums[t + 256 * i] = 0.0f;
    }
}

// =============================================================================
// Dispatch 2: both GEMMs. H = Xb @ Wt^T + bias, stored bf16; fused BN stats.
// grid = (320, 2): bx<64 -> gemm1 (M=8192), else gemm2 (M=32768).
// tile 128x128, 4 waves, wave = 64x64 as 4x4 MFMA 16x16x32, BK=32.
// =============================================================================
__global__ __launch_bounds__(256) void gemm_mfma_kernel(const unsigned short* __restrict__ Xb1,
                                                        const unsigned short* __restrict__ Xb2,
                                                        const unsigned short* __restrict__ Wt1,
                                                        const unsigned short* __restrict__ Wt2,
                                                        const float* __restrict__ b1,
                                                        const float* __restrict__ b2,
                                                        unsigned short* __restrict__ h1b,
                                                        unsigned short* __restrict__ h2b,
                                                        float* __restrict__ sums) {
    __shared__ unsigned short As[128 * 32];
    __shared__ unsigned short Bs[128 * 32];

    const int bx   = blockIdx.x;
    const bool g2  = bx >= 64;
    const unsigned short* Xb = g2 ? Xb2 : Xb1;
    const unsigned short* Wt = g2 ? Wt2 : Wt1;
    const float* bias        = g2 ? b2 : b1;
    unsigned short* Hb       = g2 ? h2b : h1b;
    float* sum               = sums + (g2 ? 512 : 0);
    float* sumsq             = sum + 256;
    const int row0 = (g2 ? bx - 64 : bx) * 128;
    const int n0   = blockIdx.y * 128;

    const int t    = threadIdx.x;
    const int wave = t >> 6;
    const int lane = t & 63;
    const int wm   = (wave & 1) * 64;
    const int wn   = (wave >> 1) * 64;
    const int ml   = lane & 15;
    const int q    = lane >> 4;

    f32x4 acc[4][4] = {};

    for (int kt = 0; kt < 256; kt += 32) {
        #pragma unroll
        for (int r = 0; r < 2; ++r) {
            const int e   = r * 2048 + t * 8;
            const int row = e >> 5;
            const int kk  = e & 31;
            async16(Xb + (size_t)(row0 + row) * 256 + kt + kk, (unsigned short*)As + e);
            async16(Wt + (size_t)(n0 + row) * 256 + kt + kk, (unsigned short*)Bs + e);
        }
        __syncthreads();

        bf16x8 af[4], bfr[4];
        #pragma unroll
        for (int mt = 0; mt < 4; ++mt)
            af[mt] = *(const bf16x8*)&As[(wm + mt * 16 + ml) * 32 + q * 8];
        #pragma unroll
        for (int nt = 0; nt < 4; ++nt)
            bfr[nt] = *(const bf16x8*)&Bs[(wn + nt * 16 + ml) * 32 + q * 8];
        #pragma unroll
        for (int mt = 0; mt < 4; ++mt)
            #pragma unroll
            for (int nt = 0; nt < 4; ++nt)
                acc[mt][nt] = __builtin_amdgcn_mfma_f32_16x16x32_bf16(af[mt], bfr[nt],
                                                                      acc[mt][nt], 0, 0, 0);
        __syncthreads();
    }

    float bv[4], psum[4], psq[4];
    #pragma unroll
    for (int nt = 0; nt < 4; ++nt) {
        bv[nt] = bias[n0 + wn + nt * 16 + ml];
        psum[nt] = 0.0f; psq[nt] = 0.0f;
    }
    #pragma unroll
    for (int mt = 0; mt < 4; ++mt)
        #pragma unroll
        for (int nt = 0; nt < 4; ++nt)
            #pragma unroll
            for (int r = 0; r < 4; ++r) {
                const float v = acc[mt][nt][r] + bv[nt];
                const int grow = row0 + wm + mt * 16 + q * 4 + r;
                Hb[(size_t)grow * 256 + n0 + wn + nt * 16 + ml] = f2bf(v);
                psum[nt] += v;
                psq[nt]  = fmaf(v, v, psq[nt]);
            }
    #pragma unroll
    for (int nt = 0; nt < 4; ++nt) {
        psum[nt] += __shfl_xor(psum[nt], 16, 64);
        psum[nt] += __shfl_xor(psum[nt], 32, 64);
        psq[nt]  += __shfl_xor(psq[nt], 16, 64);
        psq[nt]  += __shfl_xor(psq[nt], 32, 64);
    }
    if (q == 0) {
        #pragma unroll
        for (int nt = 0; nt < 4; ++nt) {
            const int col = n0 + wn + nt * 16 + ml;
            atomicAdd(&sum[col],   psum[nt]);
            atomicAdd(&sumsq[col], psq[nt]);
        }
    }
}

// =============================================================================
// Dispatch 3: fused kNN + merge + BN-fold + interpolate + add + tail.
// block = 512 threads handles 128 queries; grid = 256 blocks.
// Phase A: stage 2048 batch points (32 KB LDS), compute BN scale/shift.
// Phase B: knn — wave w scans points [w*256,(w+1)*256); lane handles
//          queries (qbase+lane, qbase+64+lane). Branchless top-3.
// Phase C: per-query merge of 8 partials (threads 0..127).
// Phase D: interp 128 q x 256 f; f = t&255, half = t>>8.
// Phase E: grid-strided passthrough tail (1 elem/thread exactly).
// =============================================================================
__global__ __launch_bounds__(512) void fused_kernel(const float* __restrict__ p1,
                                                    const float* __restrict__ p2,
                                                    const unsigned short* __restrict__ h1b,
                                                    const unsigned short* __restrict__ h2b,
                                                    const float* __restrict__ sums,
                                                    const float* __restrict__ g1,
                                                    const float* __restrict__ be1,
                                                    const float* __restrict__ g2,
                                                    const float* __restrict__ be2,
                                                    float* __restrict__ out) {
    __shared__ float4 pts[N1];            // 32 KB
    __shared__ float  pdl[8][128][3];     // 12 KB
    __shared__ int    pil[8][128][3];     // 12 KB
    __shared__ float  wql[128][3];        //  1.5 KB
    __shared__ int    jql[128][3];        //  1.5 KB
    __shared__ float  ssl[4][256];        //  4 KB   (s1,t1,s2,t2)

    const int t     = threadIdx.x;
    const int bx    = blockIdx.x;
    const int qbase = bx * 128;
    const int b     = bx >> 6;            // batch index
    const int wave  = t >> 6;
    const int lane  = t & 63;

    // ---- Phase A: stage points + BN fold ----
    #pragma unroll
    for (int r = 0; r < 4; ++r) {
        const int j = t * 4 + r;
        const size_t base = (size_t)(b * N1 + j) * 3;
        pts[j] = make_float4(p1[base + 0], p1[base + 1], p1[base + 2], 0.0f);
    }
    if (t < 256) {
        const float m1 = sums[t] * (1.0f / (float)NTOT1);
        const float v1 = sums[256 + t] * (1.0f / (float)NTOT1) - m1 * m1;
        const float s1 = g1[t] * rsqrtf(v1 + BN_EPS);
        ssl[0][t] = s1;
        ssl[1][t] = be1[t] - m1 * s1;
        const float m2 = sums[512 + t] * (1.0f / (float)NTOT2);
        const float v2 = sums[768 + t] * (1.0f / (float)NTOT2) - m2 * m2;
        const float s2 = g2[t] * rsqrtf(v2 + BN_EPS);
        ssl[2][t] = s2;
        ssl[3][t] = be2[t] - m2 * s2;
    }
    __syncthreads();

    // ---- Phase B: branchless knn, 2 queries/thread, 256-pt slice ----
    {
        const int iq0 = qbase + lane;
        const int iq1 = qbase + 64 + lane;
        const float qx0 = p2[(size_t)iq0 * 3 + 0];
        const float qy0 = p2[(size_t)iq0 * 3 + 1];
        const float qz0 = p2[(size_t)iq0 * 3 + 2];
        const float qx1 = p2[(size_t)iq1 * 3 + 0];
        const float qy1 = p2[(size_t)iq1 * 3 + 1];
        const float qz1 = p2[(size_t)iq1 * 3 + 2];

        float a0 = 1e30f, a1 = 1e30f, a2 = 1e30f; int ai0 = 0, ai1 = 0, ai2 = 0;
        float c0 = 1e30f, c1 = 1e30f, c2 = 1e30f; int ci0 = 0, ci1 = 0, ci2 = 0;

        const int jb = wave * 256;
        #pragma unroll 8
        for (int jj = 0; jj < 256; ++jj) {
            const float4 p = pts[jb + jj];   // wave-uniform broadcast
            {
                const float dx = p.x - qx0, dy = p.y - qy0, dz = p.z - qz0;
                float d = dx * dx; d = fmaf(dy, dy, d); d = fmaf(dz, dz, d);
                ins3b(d, jj, a0, a1, a2, ai0, ai1, ai2);
            }
            {
                const float dx = p.x - qx1, dy = p.y - qy1, dz = p.z - qz1;
                float d = dx * dx; d = fmaf(dy, dy, d); d = fmaf(dz, dz, d);
                ins3b(d, jj, c0, c1, c2, ci0, ci1, ci2);
            }
        }
        pdl[wave][lane][0] = a0; pdl[wave][lane][1] = a1; pdl[wave][lane][2] = a2;
        pil[wave][lane][0] = jb + ai0; pil[wave][lane][1] = jb + ai1; pil[wave][lane][2] = jb + ai2;
        pdl[wave][64 + lane][0] = c0; pdl[wave][64 + lane][1] = c1; pdl[wave][64 + lane][2] = c2;
        pil[wave][64 + lane][0] = jb + ci0; pil[wave][64 + lane][1] = jb + ci1; pil[wave][64 + lane][2] = jb + ci2;
    }
    __syncthreads();

    // ---- Phase C: merge 8 partials per query (ascending slice = ascending idx) ----
    if (t < 128) {
        float d0 = 1e30f, d1 = 1e30f, d2 = 1e30f;
        int   j0 = 0,     j1 = 0,     j2 = 0;
        #pragma unroll
        for (int s = 0; s < 8; ++s)
            #pragma unroll
            for (int k = 0; k < 3; ++k)
                ins3b(pdl[s][t][k], pil[s][t][k], d0, d1, d2, j0, j1, j2);

        const float w0 = 1.0f / fmaxf(d0, 1e-16f);
        const float w1 = 1.0f / fmaxf(d1, 1e-16f);
        const float w2 = 1.0f / fmaxf(d2, 1e-16f);
        const float inv = 1.0f / (w0 + w1 + w2);
        wql[t][0] = w0 * inv; wql[t][1] = w1 * inv; wql[t][2] = w2 * inv;
        jql[t][0] = b * N1 + j0; jql[t][1] = b * N1 + j1; jql[t][2] = b * N1 + j2;
    }
    __syncthreads();

    // ---- Phase D: interpolate + BN-apply + add ----
    {
        const int f    = t & 255;
        const int half = t >> 8;
        const float s1 = ssl[0][f], t1 = ssl[1][f];
        const float s2 = ssl[2][f], t2 = ssl[3][f];

        for (int qq = 0; qq < 64; ++qq) {
            const int v = half * 64 + qq;         // query slot (wave-uniform)
            const int i = qbase + v;
            const int   j0 = jql[v][0], j1 = jql[v][1], j2 = jql[v][2];
            const float w0 = wql[v][0], w1 = wql[v][1], w2 = wql[v][2];

            float a = w0 * bf2f(h1b[(size_t)j0 * F + f]);
            a = fmaf(w1, bf2f(h1b[(size_t)j1 * F + f]), a);
            a = fmaf(w2, bf2f(h1b[(size_t)j2 * F + f]), a);
            const float h2v = bf2f(h2b[(size_t)i * F + f]);
            out[(size_t)i * F + f] = fmaf(a, s1, t1) + fmaf(h2v, s2, t2);
        }
    }

    // ---- Phase E: passthrough tail (exactly 1 element per thread) ----
    {
        const int tid = bx * 512 + t;             // [0, 131072)
        if (tid < NTOT2 * 3) {
            out[(size_t)NTOT2 * F + tid] = p2[tid];
        } else {
            const int e = tid - NTOT2 * 3;        // [0, 32768)
            out[(size_t)NTOT2 * F + NTOT2 * 3 + e] = (float)(e >> 13);
        }
    }
}

// -----------------------------------------------------------------------------
extern "C" void kernel_launch(void* const* d_in, const int* in_sizes, int n_in,
                              void* d_out, int out_size, void* d_ws, size_t ws_size,
                              hipStream_t stream) {
    const float* f1  = (const float*)d_in[0];
    const float* p1  = (const float*)d_in[1];
    const float* f2  = (const float*)d_in[3];
    const float* p2  = (const float*)d_in[4];
    const float* W1  = (const float*)d_in[6];
    const float* b1  = (const float*)d_in[7];
    const float* g1  = (const float*)d_in[8];
    const float* be1 = (const float*)d_in[9];
    const float* W2  = (const float*)d_in[10];
    const float* b2  = (const float*)d_in[11];
    const float* g2  = (const float*)d_in[12];
    const float* be2 = (const float*)d_in[13];

    char* ws = (char*)d_ws;
    unsigned short* Xb1  = (unsigned short*)(ws);               //  4,194,304
    unsigned short* Xb2  = (unsigned short*)(ws + 4194304);     // 16,777,216
    unsigned short* Wt1  = (unsigned short*)(ws + 20971520);    //    131,072
    unsigned short* Wt2  = (unsigned short*)(ws + 21102592);    //    131,072
    unsigned short* h1b  = (unsigned short*)(ws + 21233664);    //  4,194,304
    unsigned short* h2b  = (unsigned short*)(ws + 25427968);    // 16,777,216
    float*          sums = (float*)(ws + 42205184);             //      4,096
    float*          out  = (float*)d_out;

    prep_kernel<<<10273, 256, 0, stream>>>((const float4*)f1, (const float4*)f2,
                                           W1, W2, (ushort4*)Xb1, (ushort4*)Xb2,
                                           Wt1, Wt2, sums);

    dim3 gg(320, 2);
    gemm_mfma_kernel<<<gg, 256, 0, stream>>>(Xb1, Xb2, Wt1, Wt2, b1, b2,
                                             h1b, h2b, sums);

    fused_kernel<<<256, 512, 0, stream>>>(p1, p2, h1b, h2b, sums,
                                          g1, be1, g2, be2, out);
}

// Round 6
// 185.421 us; speedup vs baseline: 2.8258x; 1.0575x over previous
//
#include <hip/hip_runtime.h>
#include <math.h>

#define BATCH   4
#define N1      2048
#define N2      8192
#define F       256
#define NTOT1   (BATCH * N1)    // 8192
#define NTOT2   (BATCH * N2)    // 32768
#define BN_EPS  1e-5f

typedef __attribute__((ext_vector_type(8))) short bf16x8;
typedef __attribute__((ext_vector_type(4))) float f32x4;

// ---------------- helpers ----------------------------------------------------
__device__ __forceinline__ unsigned short f2bf(float f) {   // RNE f32->bf16
    unsigned u = __float_as_uint(f);
    unsigned r = (u + 0x7fffu + ((u >> 16) & 1u)) >> 16;
    return (unsigned short)r;
}
__device__ __forceinline__ float bflo(unsigned u) {         // low bf16 of pair
    return __uint_as_float(u << 16);
}
__device__ __forceinline__ float bfhi(unsigned u) {         // high bf16 of pair
    return __uint_as_float(u & 0xffff0000u);
}
__device__ __forceinline__ void async16(const void* g, void* l) {
    __builtin_amdgcn_global_load_lds(
        (const __attribute__((address_space(1))) unsigned int*)g,
        (__attribute__((address_space(3))) unsigned int*)l, 16, 0, 0);
}
__device__ __forceinline__ void ins3b(float d, int j,
                                      float& d0, float& d1, float& d2,
                                      int& j0, int& j1, int& j2) {
    const bool c0 = d < d0;
    const bool c1 = d < d1;
    const bool c2 = d < d2;
    d2 = c1 ? d1 : (c2 ? d : d2);
    j2 = c1 ? j1 : (c2 ? j : j2);
    d1 = c0 ? d0 : (c1 ? d : d1);
    j1 = c0 ? j0 : (c1 ? j : j1);
    d0 = c0 ? d  : d0;
    j0 = c0 ? j  : j0;
}

// =============================================================================
// Dispatch 1: prep — X->bf16, W->bf16 transposed, zero stats. Flattened grid.
// =============================================================================
__global__ __launch_bounds__(256) void prep_kernel(const float4* __restrict__ f1,
                                                   const float4* __restrict__ f2,
                                                   const float* __restrict__ W1,
                                                   const float* __restrict__ W2,
                                                   ushort4* __restrict__ Xb1,
                                                   ushort4* __restrict__ Xb2,
                                                   unsigned short* __restrict__ Wt1,
                                                   unsigned short* __restrict__ Wt2,
                                                   float* __restrict__ sums) {
    const int bx = blockIdx.x;
    const int t  = threadIdx.x;

    if (bx < 8192) {                      // f2 -> Xb2
        const int i = bx * 256 + t;
        const float4 v = f2[i];
        ushort4 o;
        o.x = f2bf(v.x); o.y = f2bf(v.y); o.z = f2bf(v.z); o.w = f2bf(v.w);
        Xb2[i] = o;
    } else if (bx < 10240) {              // f1 -> Xb1
        const int i = (bx - 8192) * 256 + t;
        const float4 v = f1[i];
        ushort4 o;
        o.x = f2bf(v.x); o.y = f2bf(v.y); o.z = f2bf(v.z); o.w = f2bf(v.w);
        Xb1[i] = o;
    } else if (bx < 10272) {              // W transpose+convert
        __shared__ float tile[64][65];
        const int bb = bx - 10240;
        const bool second = bb >= 16;
        const int bl = second ? bb - 16 : bb;
        const float* W = second ? W2 : W1;
        unsigned short* Wt = second ? Wt2 : Wt1;
        const int gx0 = (bl & 3) * 64;    // n block
        const int gy0 = (bl >> 2) * 64;   // k block
        const int tx = t & 63;
        const int ty = t >> 6;
        #pragma unroll
        for (int j = 0; j < 16; ++j) {
            const int row = ty * 16 + j;
            tile[row][tx] = W[(size_t)(gy0 + row) * 256 + gx0 + tx];
        }
        __syncthreads();
        #pragma unroll
        for (int j = 0; j < 16; ++j) {
            const int row = ty * 16 + j;
            Wt[(size_t)(gx0 + row) * 256 + gy0 + tx] = f2bf(tile[tx][row]);
        }
    } else {                              // zero sums
        #pragma unroll
        for (int i = 0; i < 4; ++i) sums[t + 256 * i] = 0.0f;
    }
}

// =============================================================================
// Dispatch 2: both GEMMs. H = Xb @ Wt^T + bias, stored bf16; fused BN stats.
// grid = (320, 2): bx<64 -> gemm1 (M=8192), else gemm2 (M=32768).
// =============================================================================
__global__ __launch_bounds__(256) void gemm_mfma_kernel(const unsigned short* __restrict__ Xb1,
                                                        const unsigned short* __restrict__ Xb2,
                                                        const unsigned short* __restrict__ Wt1,
                                                        const unsigned short* __restrict__ Wt2,
                                                        const float* __restrict__ b1,
                                                        const float* __restrict__ b2,
                                                        unsigned short* __restrict__ h1b,
                                                        unsigned short* __restrict__ h2b,
                                                        float* __restrict__ sums) {
    __shared__ unsigned short As[128 * 32];
    __shared__ unsigned short Bs[128 * 32];

    const int bx   = blockIdx.x;
    const bool g2  = bx >= 64;
    const unsigned short* Xb = g2 ? Xb2 : Xb1;
    const unsigned short* Wt = g2 ? Wt2 : Wt1;
    const float* bias        = g2 ? b2 : b1;
    unsigned short* Hb       = g2 ? h2b : h1b;
    float* sum               = sums + (g2 ? 512 : 0);
    float* sumsq             = sum + 256;
    const int row0 = (g2 ? bx - 64 : bx) * 128;
    const int n0   = blockIdx.y * 128;

    const int t    = threadIdx.x;
    const int wave = t >> 6;
    const int lane = t & 63;
    const int wm   = (wave & 1) * 64;
    const int wn   = (wave >> 1) * 64;
    const int ml   = lane & 15;
    const int q    = lane >> 4;

    f32x4 acc[4][4] = {};

    for (int kt = 0; kt < 256; kt += 32) {
        #pragma unroll
        for (int r = 0; r < 2; ++r) {
            const int e   = r * 2048 + t * 8;
            const int row = e >> 5;
            const int kk  = e & 31;
            async16(Xb + (size_t)(row0 + row) * 256 + kt + kk, (unsigned short*)As + e);
            async16(Wt + (size_t)(n0 + row) * 256 + kt + kk, (unsigned short*)Bs + e);
        }
        __syncthreads();

        bf16x8 af[4], bfr[4];
        #pragma unroll
        for (int mt = 0; mt < 4; ++mt)
            af[mt] = *(const bf16x8*)&As[(wm + mt * 16 + ml) * 32 + q * 8];
        #pragma unroll
        for (int nt = 0; nt < 4; ++nt)
            bfr[nt] = *(const bf16x8*)&Bs[(wn + nt * 16 + ml) * 32 + q * 8];
        #pragma unroll
        for (int mt = 0; mt < 4; ++mt)
            #pragma unroll
            for (int nt = 0; nt < 4; ++nt)
                acc[mt][nt] = __builtin_amdgcn_mfma_f32_16x16x32_bf16(af[mt], bfr[nt],
                                                                      acc[mt][nt], 0, 0, 0);
        __syncthreads();
    }

    float bv[4], psum[4], psq[4];
    #pragma unroll
    for (int nt = 0; nt < 4; ++nt) {
        bv[nt] = bias[n0 + wn + nt * 16 + ml];
        psum[nt] = 0.0f; psq[nt] = 0.0f;
    }
    #pragma unroll
    for (int mt = 0; mt < 4; ++mt)
        #pragma unroll
        for (int nt = 0; nt < 4; ++nt)
            #pragma unroll
            for (int r = 0; r < 4; ++r) {
                const float v = acc[mt][nt][r] + bv[nt];
                const int grow = row0 + wm + mt * 16 + q * 4 + r;
                Hb[(size_t)grow * 256 + n0 + wn + nt * 16 + ml] = f2bf(v);
                psum[nt] += v;
                psq[nt]  = fmaf(v, v, psq[nt]);
            }
    #pragma unroll
    for (int nt = 0; nt < 4; ++nt) {
        psum[nt] += __shfl_xor(psum[nt], 16, 64);
        psum[nt] += __shfl_xor(psum[nt], 32, 64);
        psq[nt]  += __shfl_xor(psq[nt], 16, 64);
        psq[nt]  += __shfl_xor(psq[nt], 32, 64);
    }
    if (q == 0) {
        #pragma unroll
        for (int nt = 0; nt < 4; ++nt) {
            const int col = n0 + wn + nt * 16 + ml;
            atomicAdd(&sum[col],   psum[nt]);
            atomicAdd(&sumsq[col], psq[nt]);
        }
    }
}

// =============================================================================
// Dispatch 3: fused kNN + merge + BN-fold + interpolate + add + tail.
// grid = 512 blocks x 512 threads; block handles 64 queries (2 blocks/CU).
// Phase A: stage 2048 batch points SoA (24 KB) + BN scale/shift.
// Phase B: wave w scans slice [w*256,(w+1)*256), 1 query/lane, SoA float4
//          reads = 4 points per 3 LDS reads. Branchless top-3.
// Phase C: threads 0..63 merge 8 partials/query.
// Phase D: interp — thread = (feature-pair, query-group), uint bf16-pair loads.
// Phase E: passthrough tail, 256 elems/block.
// =============================================================================
__global__ __launch_bounds__(512) void fused_kernel(const float* __restrict__ p1,
                                                    const float* __restrict__ p2,
                                                    const unsigned short* __restrict__ h1b,
                                                    const unsigned short* __restrict__ h2b,
                                                    const float* __restrict__ sums,
                                                    const float* __restrict__ g1,
                                                    const float* __restrict__ be1,
                                                    const float* __restrict__ g2,
                                                    const float* __restrict__ be2,
                                                    float* __restrict__ out) {
    __shared__ float px[N1], py[N1], pz[N1];   // 24 KB SoA
    __shared__ float pdl[8][64][3];            //  6 KB
    __shared__ int   pil[8][64][3];            //  6 KB
    __shared__ float wql[64][3];               //  768 B
    __shared__ int   jql[64][3];               //  768 B
    __shared__ float ssl[4][256];              //  4 KB  (s1,t1,s2,t2)

    const int t     = threadIdx.x;
    const int bx    = blockIdx.x;
    const int qbase = bx * 64;
    const int b     = bx >> 7;                 // 128 blocks per batch
    const int wave  = t >> 6;
    const int lane  = t & 63;

    // ---- Phase A: stage points (SoA) + BN fold ----
    #pragma unroll
    for (int r = 0; r < 4; ++r) {
        const int j = r * 512 + t;
        const size_t base = (size_t)(b * N1 + j) * 3;
        px[j] = p1[base + 0];
        py[j] = p1[base + 1];
        pz[j] = p1[base + 2];
    }
    if (t < 256) {
        const float m1 = sums[t] * (1.0f / (float)NTOT1);
        const float v1 = sums[256 + t] * (1.0f / (float)NTOT1) - m1 * m1;
        const float s1 = g1[t] * rsqrtf(v1 + BN_EPS);
        ssl[0][t] = s1;
        ssl[1][t] = be1[t] - m1 * s1;
        const float m2 = sums[512 + t] * (1.0f / (float)NTOT2);
        const float v2 = sums[768 + t] * (1.0f / (float)NTOT2) - m2 * m2;
        const float s2 = g2[t] * rsqrtf(v2 + BN_EPS);
        ssl[2][t] = s2;
        ssl[3][t] = be2[t] - m2 * s2;
    }
    __syncthreads();

    // ---- Phase B: branchless knn, 1 query/lane, 256-pt slice per wave ----
    {
        const int iq = qbase + lane;
        const float qx = p2[(size_t)iq * 3 + 0];
        const float qy = p2[(size_t)iq * 3 + 1];
        const float qz = p2[(size_t)iq * 3 + 2];

        float d0 = 1e30f, d1 = 1e30f, d2 = 1e30f;
        int   i0 = 0,     i1 = 0,     i2 = 0;

        const int jb = wave * 256;
        #pragma unroll 2
        for (int jj = 0; jj < 256; jj += 4) {
            const float4 x4 = *(const float4*)&px[jb + jj];
            const float4 y4 = *(const float4*)&py[jb + jj];
            const float4 z4 = *(const float4*)&pz[jb + jj];
            {
                const float dx = x4.x - qx, dy = y4.x - qy, dz = z4.x - qz;
                float d = dx * dx; d = fmaf(dy, dy, d); d = fmaf(dz, dz, d);
                ins3b(d, jj + 0, d0, d1, d2, i0, i1, i2);
            }
            {
                const float dx = x4.y - qx, dy = y4.y - qy, dz = z4.y - qz;
                float d = dx * dx; d = fmaf(dy, dy, d); d = fmaf(dz, dz, d);
                ins3b(d, jj + 1, d0, d1, d2, i0, i1, i2);
            }
            {
                const float dx = x4.z - qx, dy = y4.z - qy, dz = z4.z - qz;
                float d = dx * dx; d = fmaf(dy, dy, d); d = fmaf(dz, dz, d);
                ins3b(d, jj + 2, d0, d1, d2, i0, i1, i2);
            }
            {
                const float dx = x4.w - qx, dy = y4.w - qy, dz = z4.w - qz;
                float d = dx * dx; d = fmaf(dy, dy, d); d = fmaf(dz, dz, d);
                ins3b(d, jj + 3, d0, d1, d2, i0, i1, i2);
            }
        }
        pdl[wave][lane][0] = d0; pdl[wave][lane][1] = d1; pdl[wave][lane][2] = d2;
        pil[wave][lane][0] = jb + i0; pil[wave][lane][1] = jb + i1; pil[wave][lane][2] = jb + i2;
    }
    __syncthreads();

    // ---- Phase C: merge 8 partials per query (ascending slice order) ----
    if (t < 64) {
        float d0 = 1e30f, d1 = 1e30f, d2 = 1e30f;
        int   j0 = 0,     j1 = 0,     j2 = 0;
        #pragma unroll
        for (int s = 0; s < 8; ++s)
            #pragma unroll
            for (int k = 0; k < 3; ++k)
                ins3b(pdl[s][t][k], pil[s][t][k], d0, d1, d2, j0, j1, j2);

        const float w0 = 1.0f / fmaxf(d0, 1e-16f);
        const float w1 = 1.0f / fmaxf(d1, 1e-16f);
        const float w2 = 1.0f / fmaxf(d2, 1e-16f);
        const float inv = 1.0f / (w0 + w1 + w2);
        wql[t][0] = w0 * inv; wql[t][1] = w1 * inv; wql[t][2] = w2 * inv;
        jql[t][0] = b * N1 + j0; jql[t][1] = b * N1 + j1; jql[t][2] = b * N1 + j2;
    }
    __syncthreads();

    // ---- Phase D: interpolate + BN-apply + add (2 features/thread) ----
    {
        const int fp = t & 127;            // feature pair
        const int f0 = fp * 2;
        const int qg = t >> 7;             // query group (0..3), 16 queries each
        const float s1a = ssl[0][f0], t1a = ssl[1][f0];
        const float s2a = ssl[2][f0], t2a = ssl[3][f0];
        const float s1b = ssl[0][f0 + 1], t1b = ssl[1][f0 + 1];
        const float s2b = ssl[2][f0 + 1], t2b = ssl[3][f0 + 1];

        for (int qq = 0; qq < 16; ++qq) {
            const int v = qg * 16 + qq;
            const int i = qbase + v;
            const int   j0 = jql[v][0], j1 = jql[v][1], j2 = jql[v][2];
            const float w0 = wql[v][0], w1 = wql[v][1], w2 = wql[v][2];

            const unsigned u0 = *(const unsigned*)(h1b + (size_t)j0 * F + f0);
            const unsigned u1 = *(const unsigned*)(h1b + (size_t)j1 * F + f0);
            const unsigned u2 = *(const unsigned*)(h1b + (size_t)j2 * F + f0);
            const unsigned uh = *(const unsigned*)(h2b + (size_t)i * F + f0);

            float alo = w0 * bflo(u0);
            alo = fmaf(w1, bflo(u1), alo);
            alo = fmaf(w2, bflo(u2), alo);
            float ahi = w0 * bfhi(u0);
            ahi = fmaf(w1, bfhi(u1), ahi);
            ahi = fmaf(w2, bfhi(u2), ahi);

            float2 o;
            o.x = fmaf(alo, s1a, t1a) + fmaf(bflo(uh), s2a, t2a);
            o.y = fmaf(ahi, s1b, t1b) + fmaf(bfhi(uh), s2b, t2b);
            *(float2*)(out + (size_t)i * F + f0) = o;
        }
    }

    // ---- Phase E: passthrough tail (256 elems per block) ----
    if (t < 256) {
        const int tid = bx * 256 + t;              // [0, 131072)
        if (tid < NTOT2 * 3) {
            out[(size_t)NTOT2 * F + tid] = p2[tid];
        } else {
            const int e = tid - NTOT2 * 3;         // [0, 32768)
            out[(size_t)NTOT2 * F + NTOT2 * 3 + e] = (float)(e >> 13);
        }
    }
}

// -----------------------------------------------------------------------------
extern "C" void kernel_launch(void* const* d_in, const int* in_sizes, int n_in,
                              void* d_out, int out_size, void* d_ws, size_t ws_size,
                              hipStream_t stream) {
    const float* f1  = (const float*)d_in[0];
    const float* p1  = (const float*)d_in[1];
    const float* f2  = (const float*)d_in[3];
    const float* p2  = (const float*)d_in[4];
    const float* W1  = (const float*)d_in[6];
    const float* b1  = (const float*)d_in[7];
    const float* g1  = (const float*)d_in[8];
    const float* be1 = (const float*)d_in[9];
    const float* W2  = (const float*)d_in[10];
    const float* b2  = (const float*)d_in[11];
    const float* g2  = (const float*)d_in[12];
    const float* be2 = (const float*)d_in[13];

    char* ws = (char*)d_ws;
    unsigned short* Xb1  = (unsigned short*)(ws);               //  4,194,304
    unsigned short* Xb2  = (unsigned short*)(ws + 4194304);     // 16,777,216
    unsigned short* Wt1  = (unsigned short*)(ws + 20971520);    //    131,072
    unsigned short* Wt2  = (unsigned short*)(ws + 21102592);    //    131,072
    unsigned short* h1b  = (unsigned short*)(ws + 21233664);    //  4,194,304
    unsigned short* h2b  = (unsigned short*)(ws + 25427968);    // 16,777,216
    float*          sums = (float*)(ws + 42205184);             //      4,096
    float*          out  = (float*)d_out;

    prep_kernel<<<10273, 256, 0, stream>>>((const float4*)f1, (const float4*)f2,
                                           W1, W2, (ushort4*)Xb1, (ushort4*)Xb2,
                                           Wt1, Wt2, sums);

    dim3 gg(320, 2);
    gemm_mfma_kernel<<<gg, 256, 0, stream>>>(Xb1, Xb2, Wt1, Wt2, b1, b2,
                                             h1b, h2b, sums);

    fused_kernel<<<512, 512, 0, stream>>>(p1, p2, h1b, h2b, sums,
                                          g1, be1, g2, be2, out);
}

// Round 9
// 183.542 us; speedup vs baseline: 2.8548x; 1.0102x over previous
//
#include <hip/hip_runtime.h>
#include <math.h>

#define BATCH   4
#define N1      2048
#define N2      8192
#define F       256
#define NTOT1   (BATCH * N1)    // 8192
#define NTOT2   (BATCH * N2)    // 32768
#define BN_EPS  1e-5f

typedef __attribute__((ext_vector_type(8))) short bf16x8;
typedef __attribute__((ext_vector_type(4))) float f32x4;

// ---------------- helpers ----------------------------------------------------
__device__ __forceinline__ unsigned short f2bf(float f) {   // RNE f32->bf16
    unsigned u = __float_as_uint(f);
    unsigned r = (u + 0x7fffu + ((u >> 16) & 1u)) >> 16;
    return (unsigned short)r;
}
__device__ __forceinline__ float bflo(unsigned u) {         // low bf16 of pair
    return __uint_as_float(u << 16);
}
__device__ __forceinline__ float bfhi(unsigned u) {         // high bf16 of pair
    return __uint_as_float(u & 0xffff0000u);
}
__device__ __forceinline__ void async16(const void* g, void* l) {
    __builtin_amdgcn_global_load_lds(
        (const __attribute__((address_space(1))) unsigned int*)g,
        (__attribute__((address_space(3))) unsigned int*)l, 16, 0, 0);
}

// branchless top-3 insert, med3 form. Invariant d0<=d1<=d2.
// distances: 2 v_med3 + 1 v_min (independent of the compares);
// indices: 3 v_cmp + 5 v_cndmask. Strict < == first-occurrence tie-break.
__device__ __forceinline__ void ins3m(float d, int j,
                                      float& d0, float& d1, float& d2,
                                      int& j0, int& j1, int& j2) {
    const bool c0 = d < d0;
    const bool c1 = d < d1;
    const bool c2 = d < d2;
    const float nd1 = __builtin_amdgcn_fmed3f(d, d0, d1);
    const float nd2 = __builtin_amdgcn_fmed3f(d, d1, d2);
    d0 = fminf(d, d0);
    d1 = nd1;
    d2 = nd2;
    j2 = c1 ? j1 : (c2 ? j : j2);
    j1 = c0 ? j0 : (c1 ? j : j1);
    j0 = c0 ? j  : j0;
}

// =============================================================================
// Dispatch 1: prep — X->bf16, W->bf16 transposed, zero stats. Flattened grid.
// =============================================================================
__global__ __launch_bounds__(256) void prep_kernel(const float4* __restrict__ f1,
                                                   const float4* __restrict__ f2,
                                                   const float* __restrict__ W1,
                                                   const float* __restrict__ W2,
                                                   ushort4* __restrict__ Xb1,
                                                   ushort4* __restrict__ Xb2,
                                                   unsigned short* __restrict__ Wt1,
                                                   unsigned short* __restrict__ Wt2,
                                                   float* __restrict__ sums) {
    const int bx = blockIdx.x;
    const int t  = threadIdx.x;

    if (bx < 8192) {                      // f2 -> Xb2
        const int i = bx * 256 + t;
        const float4 v = f2[i];
        ushort4 o;
        o.x = f2bf(v.x); o.y = f2bf(v.y); o.z = f2bf(v.z); o.w = f2bf(v.w);
        Xb2[i] = o;
    } else if (bx < 10240) {              // f1 -> Xb1
        const int i = (bx - 8192) * 256 + t;
        const float4 v = f1[i];
        ushort4 o;
        o.x = f2bf(v.x); o.y = f2bf(v.y); o.z = f2bf(v.z); o.w = f2bf(v.w);
        Xb1[i] = o;
    } else if (bx < 10272) {              // W transpose+convert
        __shared__ float tile[64][65];
        const int bb = bx - 10240;
        const bool second = bb >= 16;
        const int bl = second ? bb - 16 : bb;
        const float* W = second ? W2 : W1;
        unsigned short* Wt = second ? Wt2 : Wt1;
        const int gx0 = (bl & 3) * 64;    // n block
        const int gy0 = (bl >> 2) * 64;   // k block
        const int tx = t & 63;
        const int ty = t >> 6;
        #pragma unroll
        for (int j = 0; j < 16; ++j) {
            const int row = ty * 16 + j;
            tile[row][tx] = W[(size_t)(gy0 + row) * 256 + gx0 + tx];
        }
        __syncthreads();
        #pragma unroll
        for (int j = 0; j < 16; ++j) {
            const int row = ty * 16 + j;
            Wt[(size_t)(gx0 + row) * 256 + gy0 + tx] = f2bf(tile[tx][row]);
        }
    } else {                              // zero sums
        #pragma unroll
        for (int i = 0; i < 4; ++i) sums[t + 256 * i] = 0.0f;
    }
}

// =============================================================================
// Dispatch 2: both GEMMs. H = Xb @ Wt^T + bias, stored bf16; fused BN stats.
// grid = (320, 2): bx<64 -> gemm1 (M=8192), else gemm2 (M=32768).
// =============================================================================
__global__ __launch_bounds__(256) void gemm_mfma_kernel(const unsigned short* __restrict__ Xb1,
                                                        const unsigned short* __restrict__ Xb2,
                                                        const unsigned short* __restrict__ Wt1,
                                                        const unsigned short* __restrict__ Wt2,
                                                        const float* __restrict__ b1,
                                                        const float* __restrict__ b2,
                                                        unsigned short* __restrict__ h1b,
                                                        unsigned short* __restrict__ h2b,
                                                        float* __restrict__ sums) {
    __shared__ unsigned short As[128 * 32];
    __shared__ unsigned short Bs[128 * 32];

    const int bx   = blockIdx.x;
    const bool g2  = bx >= 64;
    const unsigned short* Xb = g2 ? Xb2 : Xb1;
    const unsigned short* Wt = g2 ? Wt2 : Wt1;
    const float* bias        = g2 ? b2 : b1;
    unsigned short* Hb       = g2 ? h2b : h1b;
    float* sum               = sums + (g2 ? 512 : 0);
    float* sumsq             = sum + 256;
    const int row0 = (g2 ? bx - 64 : bx) * 128;
    const int n0   = blockIdx.y * 128;

    const int t    = threadIdx.x;
    const int wave = t >> 6;
    const int lane = t & 63;
    const int wm   = (wave & 1) * 64;
    const int wn   = (wave >> 1) * 64;
    const int ml   = lane & 15;
    const int q    = lane >> 4;

    f32x4 acc[4][4] = {};

    for (int kt = 0; kt < 256; kt += 32) {
        #pragma unroll
        for (int r = 0; r < 2; ++r) {
            const int e   = r * 2048 + t * 8;
            const int row = e >> 5;
            const int kk  = e & 31;
            async16(Xb + (size_t)(row0 + row) * 256 + kt + kk, (unsigned short*)As + e);
            async16(Wt + (size_t)(n0 + row) * 256 + kt + kk, (unsigned short*)Bs + e);
        }
        __syncthreads();

        bf16x8 af[4], bfr[4];
        #pragma unroll
        for (int mt = 0; mt < 4; ++mt)
            af[mt] = *(const bf16x8*)&As[(wm + mt * 16 + ml) * 32 + q * 8];
        #pragma unroll
        for (int nt = 0; nt < 4; ++nt)
            bfr[nt] = *(const bf16x8*)&Bs[(wn + nt * 16 + ml) * 32 + q * 8];
        #pragma unroll
        for (int mt = 0; mt < 4; ++mt)
            #pragma unroll
            for (int nt = 0; nt < 4; ++nt)
                acc[mt][nt] = __builtin_amdgcn_mfma_f32_16x16x32_bf16(af[mt], bfr[nt],
                                                                      acc[mt][nt], 0, 0, 0);
        __syncthreads();
    }

    float bv[4], psum[4], psq[4];
    #pragma unroll
    for (int nt = 0; nt < 4; ++nt) {
        bv[nt] = bias[n0 + wn + nt * 16 + ml];
        psum[nt] = 0.0f; psq[nt] = 0.0f;
    }
    #pragma unroll
    for (int mt = 0; mt < 4; ++mt)
        #pragma unroll
        for (int nt = 0; nt < 4; ++nt)
            #pragma unroll
            for (int r = 0; r < 4; ++r) {
                const float v = acc[mt][nt][r] + bv[nt];
                const int grow = row0 + wm + mt * 16 + q * 4 + r;
                Hb[(size_t)grow * 256 + n0 + wn + nt * 16 + ml] = f2bf(v);
                psum[nt] += v;
                psq[nt]  = fmaf(v, v, psq[nt]);
            }
    #pragma unroll
    for (int nt = 0; nt < 4; ++nt) {
        psum[nt] += __shfl_xor(psum[nt], 16, 64);
        psum[nt] += __shfl_xor(psum[nt], 32, 64);
        psq[nt]  += __shfl_xor(psq[nt], 16, 64);
        psq[nt]  += __shfl_xor(psq[nt], 32, 64);
    }
    if (q == 0) {
        #pragma unroll
        for (int nt = 0; nt < 4; ++nt) {
            const int col = n0 + wn + nt * 16 + ml;
            atomicAdd(&sum[col],   psum[nt]);
            atomicAdd(&sumsq[col], psq[nt]);
        }
    }
}

// =============================================================================
// Dispatch 3: fused kNN + merge + BN-fold + interpolate + add + tail.
// grid = 512 blocks x 512 threads (R6-validated shape); block handles 64 queries.
// Phase A: stage 2048 batch points SoA (24 KB) + BN scale/shift.
// Phase B: wave w (of 8) scans slice [w*256,(w+1)*256), 1 query/lane,
//          SoA float4 reads, med3 branchless top-3.
// Phase C: threads 0..63 merge 8 partials/query.
// Phase D: interp — thread = (feature-pair, query-group of 16).
// Phase E: passthrough tail, 256 elems/block.
// =============================================================================
__global__ __launch_bounds__(512) void fused_kernel(const float* __restrict__ p1,
                                                    const float* __restrict__ p2,
                                                    const unsigned short* __restrict__ h1b,
                                                    const unsigned short* __restrict__ h2b,
                                                    const float* __restrict__ sums,
                                                    const float* __restrict__ g1,
                                                    const float* __restrict__ be1,
                                                    const float* __restrict__ g2,
                                                    const float* __restrict__ be2,
                                                    float* __restrict__ out) {
    __shared__ float px[N1], py[N1], pz[N1];   // 24 KB SoA
    __shared__ float pdl[8][64][3];            //  6 KB
    __shared__ int   pil[8][64][3];            //  6 KB
    __shared__ float wql[64][3];               //  768 B
    __shared__ int   jql[64][3];               //  768 B
    __shared__ float ssl[4][256];              //  4 KB  (s1,t1,s2,t2)

    const int t     = threadIdx.x;
    const int bx    = blockIdx.x;
    const int qbase = bx * 64;
    const int b     = bx >> 7;                 // 128 blocks per batch
    const int wave  = t >> 6;                  // 0..7
    const int lane  = t & 63;

    // ---- Phase A: stage points (SoA) + BN fold ----
    #pragma unroll
    for (int r = 0; r < 4; ++r) {
        const int j = r * 512 + t;
        const size_t base = (size_t)(b * N1 + j) * 3;
        px[j] = p1[base + 0];
        py[j] = p1[base + 1];
        pz[j] = p1[base + 2];
    }
    if (t < 256) {
        const float m1 = sums[t] * (1.0f / (float)NTOT1);
        const float v1 = sums[256 + t] * (1.0f / (float)NTOT1) - m1 * m1;
        const float s1 = g1[t] * rsqrtf(v1 + BN_EPS);
        ssl[0][t] = s1;
        ssl[1][t] = be1[t] - m1 * s1;
        const float m2 = sums[512 + t] * (1.0f / (float)NTOT2);
        const float v2 = sums[768 + t] * (1.0f / (float)NTOT2) - m2 * m2;
        const float s2 = g2[t] * rsqrtf(v2 + BN_EPS);
        ssl[2][t] = s2;
        ssl[3][t] = be2[t] - m2 * s2;
    }
    __syncthreads();

    // ---- Phase B: med3 branchless knn, 1 query/lane, 256-pt slice per wave ----
    {
        const int iq = qbase + lane;
        const float qx = p2[(size_t)iq * 3 + 0];
        const float qy = p2[(size_t)iq * 3 + 1];
        const float qz = p2[(size_t)iq * 3 + 2];

        float d0 = 1e30f, d1 = 1e30f, d2 = 1e30f;
        int   i0 = 0,     i1 = 0,     i2 = 0;

        const int jb = wave * 256;
        #pragma unroll 2
        for (int jj = 0; jj < 256; jj += 4) {
            const float4 x4 = *(const float4*)&px[jb + jj];
            const float4 y4 = *(const float4*)&py[jb + jj];
            const float4 z4 = *(const float4*)&pz[jb + jj];
            {
                const float dx = x4.x - qx, dy = y4.x - qy, dz = z4.x - qz;
                float d = dx * dx; d = fmaf(dy, dy, d); d = fmaf(dz, dz, d);
                ins3m(d, jj + 0, d0, d1, d2, i0, i1, i2);
            }
            {
                const float dx = x4.y - qx, dy = y4.y - qy, dz = z4.y - qz;
                float d = dx * dx; d = fmaf(dy, dy, d); d = fmaf(dz, dz, d);
                ins3m(d, jj + 1, d0, d1, d2, i0, i1, i2);
            }
            {
                const float dx = x4.z - qx, dy = y4.z - qy, dz = z4.z - qz;
                float d = dx * dx; d = fmaf(dy, dy, d); d = fmaf(dz, dz, d);
                ins3m(d, jj + 2, d0, d1, d2, i0, i1, i2);
            }
            {
                const float dx = x4.w - qx, dy = y4.w - qy, dz = z4.w - qz;
                float d = dx * dx; d = fmaf(dy, dy, d); d = fmaf(dz, dz, d);
                ins3m(d, jj + 3, d0, d1, d2, i0, i1, i2);
            }
        }
        pdl[wave][lane][0] = d0; pdl[wave][lane][1] = d1; pdl[wave][lane][2] = d2;
        pil[wave][lane][0] = jb + i0; pil[wave][lane][1] = jb + i1; pil[wave][lane][2] = jb + i2;
    }
    __syncthreads();

    // ---- Phase C: merge 8 partials per query (ascending slice order) ----
    if (t < 64) {
        float d0 = 1e30f, d1 = 1e30f, d2 = 1e30f;
        int   j0 = 0,     j1 = 0,     j2 = 0;
        #pragma unroll
        for (int s = 0; s < 8; ++s)
            #pragma unroll
            for (int k = 0; k < 3; ++k)
                ins3m(pdl[s][t][k], pil[s][t][k], d0, d1, d2, j0, j1, j2);

        const float w0 = 1.0f / fmaxf(d0, 1e-16f);
        const float w1 = 1.0f / fmaxf(d1, 1e-16f);
        const float w2 = 1.0f / fmaxf(d2, 1e-16f);
        const float inv = 1.0f / (w0 + w1 + w2);
        wql[t][0] = w0 * inv; wql[t][1] = w1 * inv; wql[t][2] = w2 * inv;
        jql[t][0] = b * N1 + j0; jql[t][1] = b * N1 + j1; jql[t][2] = b * N1 + j2;
    }
    __syncthreads();

    // ---- Phase D: interpolate + BN-apply + add (2 features/thread) ----
    {
        const int fp = t & 127;            // feature pair
        const int f0 = fp * 2;
        const int qg = t >> 7;             // query group (0..3), 16 queries each
        const float s1a = ssl[0][f0], t1a = ssl[1][f0];
        const float s2a = ssl[2][f0], t2a = ssl[3][f0];
        const float s1b = ssl[0][f0 + 1], t1b = ssl[1][f0 + 1];
        const float s2b = ssl[2][f0 + 1], t2b = ssl[3][f0 + 1];

        for (int qq = 0; qq < 16; ++qq) {
            const int v = qg * 16 + qq;
            const int i = qbase + v;
            const int   j0 = jql[v][0], j1 = jql[v][1], j2 = jql[v][2];
            const float w0 = wql[v][0], w1 = wql[v][1], w2 = wql[v][2];

            const unsigned u0 = *(const unsigned*)(h1b + (size_t)j0 * F + f0);
            const unsigned u1 = *(const unsigned*)(h1b + (size_t)j1 * F + f0);
            const unsigned u2 = *(const unsigned*)(h1b + (size_t)j2 * F + f0);
            const unsigned uh = *(const unsigned*)(h2b + (size_t)i * F + f0);

            float alo = w0 * bflo(u0);
            alo = fmaf(w1, bflo(u1), alo);
            alo = fmaf(w2, bflo(u2), alo);
            float ahi = w0 * bfhi(u0);
            ahi = fmaf(w1, bfhi(u1), ahi);
            ahi = fmaf(w2, bfhi(u2), ahi);

            float2 o;
            o.x = fmaf(alo, s1a, t1a) + fmaf(bflo(uh), s2a, t2a);
            o.y = fmaf(ahi, s1b, t1b) + fmaf(bfhi(uh), s2b, t2b);
            *(float2*)(out + (size_t)i * F + f0) = o;
        }
    }

    // ---- Phase E: passthrough tail (256 elems per block) ----
    if (t < 256) {
        const int tid = bx * 256 + t;              // [0, 131072)
        if (tid < NTOT2 * 3) {
            out[(size_t)NTOT2 * F + tid] = p2[tid];
        } else {
            const int e = tid - NTOT2 * 3;         // [0, 32768)
            out[(size_t)NTOT2 * F + NTOT2 * 3 + e] = (float)(e >> 13);
        }
    }
}

// -----------------------------------------------------------------------------
extern "C" void kernel_launch(void* const* d_in, const int* in_sizes, int n_in,
                              void* d_out, int out_size, void* d_ws, size_t ws_size,
                              hipStream_t stream) {
    const float* f1  = (const float*)d_in[0];
    const float* p1  = (const float*)d_in[1];
    const float* f2  = (const float*)d_in[3];
    const float* p2  = (const float*)d_in[4];
    const float* W1  = (const float*)d_in[6];
    const float* b1  = (const float*)d_in[7];
    const float* g1  = (const float*)d_in[8];
    const float* be1 = (const float*)d_in[9];
    const float* W2  = (const float*)d_in[10];
    const float* b2  = (const float*)d_in[11];
    const float* g2  = (const float*)d_in[12];
    const float* be2 = (const float*)d_in[13];

    char* ws = (char*)d_ws;
    unsigned short* Xb1  = (unsigned short*)(ws);               //  4,194,304
    unsigned short* Xb2  = (unsigned short*)(ws + 4194304);     // 16,777,216
    unsigned short* Wt1  = (unsigned short*)(ws + 20971520);    //    131,072
    unsigned short* Wt2  = (unsigned short*)(ws + 21102592);    //    131,072
    unsigned short* h1b  = (unsigned short*)(ws + 21233664);    //  4,194,304
    unsigned short* h2b  = (unsigned short*)(ws + 25427968);    // 16,777,216
    float*          sums = (float*)(ws + 42205184);             //      4,096
    float*          out  = (float*)d_out;

    prep_kernel<<<10273, 256, 0, stream>>>((const float4*)f1, (const float4*)f2,
                                           W1, W2, (ushort4*)Xb1, (ushort4*)Xb2,
                                           Wt1, Wt2, sums);

    dim3 gg(320, 2);
    gemm_mfma_kernel<<<gg, 256, 0, stream>>>(Xb1, Xb2, Wt1, Wt2, b1, b2,
                                             h1b, h2b, sums);

    fused_kernel<<<512, 512, 0, stream>>>(p1, p2, h1b, h2b, sums,
                                          g1, be1, g2, be2, out);
}